// Round 11
// baseline (791.265 us; speedup 1.0000x reference)
//
#include <hip/hip_runtime.h>
#include <hip/hip_bf16.h>

// Problem constants (S=2048, B=2, H=1024, NH=16, NKV=4, HD=64, E=8, K=2, F=4096)
constexpr int TT   = 4096;   // S*B tokens
constexpr int HH   = 1024;
constexpr int QKVN = 1536;
constexpr int FF   = 4096;

using f16x8  = __attribute__((ext_vector_type(8))) _Float16;
using f16x4  = __attribute__((ext_vector_type(4))) _Float16;
using bf16x8 = __attribute__((ext_vector_type(8))) short;
using s16x4  = __attribute__((ext_vector_type(4))) short;
using f32x4  = __attribute__((ext_vector_type(4))) float;

static __device__ __forceinline__ f32x4 mfma16(f16x8 a, f16x8 b, f32x4 c) {
  return __builtin_amdgcn_mfma_f32_16x16x32_f16(a, b, c, 0, 0, 0);
}
static __device__ __forceinline__ f32x4 mfmabf(bf16x8 a, bf16x8 b, f32x4 c) {
  return __builtin_amdgcn_mfma_f32_16x16x32_bf16(a, b, c, 0, 0, 0);
}
static __device__ __forceinline__ short f2bf(float f) {
  union { float f; unsigned u; } v; v.f = f;
  unsigned r = v.u + 0x7fffu + ((v.u >> 16) & 1u);
  return (short)(r >> 16);
}
static __device__ __forceinline__ void split16(float f, _Float16 &h, _Float16 &l) {
  _Float16 hh = (_Float16)f; h = hh; l = (_Float16)(f - (float)hh);
}
// fast tanh-gelu (max |diff| vs exact-gelu ~3e-3; hidden is bf16 anyway)
static __device__ __forceinline__ float fast_gelu(float x) {
  float u = 0.7978845608f * (x + 0.044715f * x * x * x);
  float a = __expf(-2.0f * fabsf(u));
  float t = (1.0f - a) * __builtin_amdgcn_rcpf(1.0f + a);
  t = copysignf(t, u);
  return 0.5f * x * (1.0f + t);
}
// async global->LDS, 16B per lane. LDS ptr must be wave-uniform; global ptr is per-lane.
static __device__ __forceinline__ void gload16(const void* g, void* l) {
  __builtin_amdgcn_global_load_lds((__attribute__((address_space(1))) void*)(g),
                                   (__attribute__((address_space(3))) void*)(l), 16, 0, 0);
}

__global__ void zero_cnt(int* cnt) { if (threadIdx.x < 8) cnt[threadIdx.x] = 0; }

// ---------------- weight transpose + fp16 hi/lo split: W[K][N] f32 -> out[N][K] f16 x2 ----------
__global__ __launch_bounds__(256) void wconv_split(const float* __restrict__ W,
    _Float16* __restrict__ oh, _Float16* __restrict__ ol, int K, int N)
{
  __shared__ float ts[64][68];
  int n0 = blockIdx.x * 64, k0 = blockIdx.y * 64, t = threadIdx.x;
  #pragma unroll
  for (int it = 0; it < 4; it++) {
    int el = it * 1024 + t * 4; int r = el >> 6, c = el & 63;
    float4 v = *(const float4*)&W[(size_t)(k0 + r) * N + n0 + c];
    *(float4*)&ts[r][c] = v;
  }
  __syncthreads();
  #pragma unroll
  for (int it = 0; it < 4; it++) {
    int el = it * 1024 + t * 4; int nr = el >> 6, kc = el & 63;
    f16x4 hv, lv;
    #pragma unroll
    for (int q = 0; q < 4; q++) { _Float16 hh, ll; split16(ts[kc + q][nr], hh, ll); hv[q] = hh; lv[q] = ll; }
    size_t o = (size_t)(n0 + nr) * K + k0 + kc;
    *(f16x4*)&oh[o] = hv; *(f16x4*)&ol[o] = lv;
  }
}

// ---------------- weight transpose to bf16 (batched over experts via z): W[z][K][N] -> out[z][N][K]
__global__ __launch_bounds__(256) void wconv_bf(const float* __restrict__ W,
    short* __restrict__ o, int K, int N)
{
  __shared__ float ts[64][68];
  const float* Wz = W + (size_t)blockIdx.z * K * N;
  short* oz = o + (size_t)blockIdx.z * K * N;
  int n0 = blockIdx.x * 64, k0 = blockIdx.y * 64, t = threadIdx.x;
  #pragma unroll
  for (int it = 0; it < 4; it++) {
    int el = it * 1024 + t * 4; int r = el >> 6, c = el & 63;
    float4 v = *(const float4*)&Wz[(size_t)(k0 + r) * N + n0 + c];
    *(float4*)&ts[r][c] = v;
  }
  __syncthreads();
  #pragma unroll
  for (int it = 0; it < 4; it++) {
    int el = it * 1024 + t * 4; int nr = el >> 6, kc = el & 63;
    s16x4 bv;
    #pragma unroll
    for (int q = 0; q < 4; q++) bv[q] = f2bf(ts[kc + q][nr]);
    *(s16x4*)&oz[(size_t)(n0 + nr) * K + k0 + kc] = bv;
  }
}

// ---------------- V transpose: qkv f32 V-cols -> vt[bkv][d][s] f16 hi/lo ----------------
__global__ __launch_bounds__(256) void vtrans(const float* __restrict__ qkv,
    _Float16* __restrict__ vh, _Float16* __restrict__ vl)
{
  __shared__ float ts[64][68];
  int bkv = blockIdx.x, b = bkv >> 2, kvh = bkv & 3;
  int s0 = blockIdx.y * 64, t = threadIdx.x;
  #pragma unroll
  for (int it = 0; it < 4; it++) {
    int el = it * 1024 + t * 4; int r = el >> 6, c = el & 63;
    float4 v = *(const float4*)&qkv[(size_t)((s0 + r) * 2 + b) * QKVN + 1280 + kvh * 64 + c];
    *(float4*)&ts[r][c] = v;
  }
  __syncthreads();
  #pragma unroll
  for (int it = 0; it < 4; it++) {
    int el = it * 1024 + t * 4; int d = el >> 6, sc = el & 63;
    f16x4 hv, lv;
    #pragma unroll
    for (int q = 0; q < 4; q++) { _Float16 hh, ll; split16(ts[sc + q][d], hh, ll); hv[q] = hh; lv[q] = ll; }
    size_t o = ((size_t)bkv * 64 + d) * 2048 + s0 + sc;
    *(f16x4*)&vh[o] = hv; *(f16x4*)&vl[o] = lv;
  }
}

// ---------------- LayerNorm, f32 math. MODE 0: emit fp16 hi/lo. MODE 1: emit f32 + bf16 -------
template<int MODE>
__global__ __launch_bounds__(256) void ln_split(const float* __restrict__ in,
    const float* __restrict__ wt, const float* __restrict__ bs,
    _Float16* __restrict__ oh, _Float16* __restrict__ ol,
    float* __restrict__ xo, short* __restrict__ xbo)
{
  int row = blockIdx.x, tid = threadIdx.x;
  const float4* ip = (const float4*)(in + (size_t)row * HH);
  float4 v = ip[tid];
  float s = v.x + v.y + v.z + v.w;
  #pragma unroll
  for (int m = 1; m < 64; m <<= 1) s += __shfl_xor(s, m, 64);
  __shared__ float red1[4], red2[4];
  int wid = tid >> 6;
  if ((tid & 63) == 0) red1[wid] = s;
  __syncthreads();
  float mu = (red1[0] + red1[1] + red1[2] + red1[3]) * (1.0f / HH);
  float4 c; c.x = v.x - mu; c.y = v.y - mu; c.z = v.z - mu; c.w = v.w - mu;
  float s2 = c.x*c.x + c.y*c.y + c.z*c.z + c.w*c.w;
  #pragma unroll
  for (int m = 1; m < 64; m <<= 1) s2 += __shfl_xor(s2, m, 64);
  if ((tid & 63) == 0) red2[wid] = s2;
  __syncthreads();
  float ve = (red2[0] + red2[1] + red2[2] + red2[3]) * (1.0f / HH) + 1e-5f;
  float rs = rsqrtf(ve);
  rs = rs * (1.5f - 0.5f * ve * rs * rs);
  float4 wv = ((const float4*)wt)[tid], bv = ((const float4*)bs)[tid];
  float o4[4];
  o4[0] = c.x * rs * wv.x + bv.x; o4[1] = c.y * rs * wv.y + bv.y;
  o4[2] = c.z * rs * wv.z + bv.z; o4[3] = c.w * rs * wv.w + bv.w;
  size_t base = (size_t)row * HH + tid * 4;
  if (MODE == 0) {
    f16x4 hv, lv;
    #pragma unroll
    for (int q = 0; q < 4; q++) { _Float16 hh, ll; split16(o4[q], hh, ll); hv[q] = hh; lv[q] = ll; }
    *(f16x4*)&oh[base] = hv; *(f16x4*)&ol[base] = lv;
  } else {
    float4 ov; ov.x = o4[0]; ov.y = o4[1]; ov.z = o4[2]; ov.w = o4[3];
    *(float4*)&xo[base] = ov;
    s16x4 bvv;
    #pragma unroll
    for (int q = 0; q < 4; q++) bvv[q] = f2bf(o4[q]);
    *(s16x4*)&xbo[base] = bvv;
  }
}

// ------- fp16-split GEMM, m97-style: global_load_lds staging, 128x128 tile, BK=32, 3-pass MFMA
template<int EPI>
__global__ __launch_bounds__(256) void gemm_split2(
    const _Float16* __restrict__ Agh, const _Float16* __restrict__ Agl,
    const _Float16* __restrict__ Bgh, const _Float16* __restrict__ Bgl,
    int K, float* __restrict__ C, int ldc, const float* __restrict__ resid,
    _Float16* __restrict__ kh, _Float16* __restrict__ kl)
{
  __shared__ _Float16 AhS[4096], AlS[4096], BhS[4096], BlS[4096];
  const int tid = threadIdx.x, lane = tid & 63, w = tid >> 6;
  const int wr = w >> 1, wc = w & 1;
  const int m0 = blockIdx.y * 128, n0 = blockIdx.x * 128;
  f32x4 acc[4][4] = {};
  const _Float16 *pah[2], *pal[2], *pbh[2], *pbl[2];
  int ldsb[2];
  #pragma unroll
  for (int i = 0; i < 2; i++) {
    int E = i * 2048 + w * 512 + lane * 8;
    int r = E >> 5, cc = E & 31;
    int cs = cc ^ ((r & 3) << 3);
    pah[i] = Agh + (size_t)(m0 + r) * K + cs;
    pal[i] = Agl + (size_t)(m0 + r) * K + cs;
    pbh[i] = Bgh + (size_t)(n0 + r) * K + cs;
    pbl[i] = Bgl + (size_t)(n0 + r) * K + cs;
    ldsb[i] = i * 2048 + w * 512;
  }
  const int rr = lane & 15, ko = (lane >> 4) * 8;
  const int xo = (rr & 3) << 3;
  for (int k0 = 0; k0 < K; k0 += 32) {
    __syncthreads();
    #pragma unroll
    for (int i = 0; i < 2; i++) {
      gload16(pah[i] + k0, &AhS[ldsb[i]]);
      gload16(pal[i] + k0, &AlS[ldsb[i]]);
      gload16(pbh[i] + k0, &BhS[ldsb[i]]);
      gload16(pbl[i] + k0, &BlS[ldsb[i]]);
    }
    __syncthreads();
    f16x8 fah[4], fal[4], fbh[4], fbl[4];
    #pragma unroll
    for (int m = 0; m < 4; m++) {
      int ro = (wr * 64 + m * 16 + rr) * 32 + (ko ^ xo);
      fah[m] = *(const f16x8*)&AhS[ro];
      fal[m] = *(const f16x8*)&AlS[ro];
    }
    #pragma unroll
    for (int n = 0; n < 4; n++) {
      int ro = (wc * 64 + n * 16 + rr) * 32 + (ko ^ xo);
      fbh[n] = *(const f16x8*)&BhS[ro];
      fbl[n] = *(const f16x8*)&BlS[ro];
    }
    #pragma unroll
    for (int m = 0; m < 4; m++)
      #pragma unroll
      for (int n = 0; n < 4; n++) {
        acc[m][n] = mfma16(fah[m], fbh[n], acc[m][n]);
        acc[m][n] = mfma16(fah[m], fbl[n], acc[m][n]);
        acc[m][n] = mfma16(fal[m], fbh[n], acc[m][n]);
      }
  }
  int r0 = m0 + wr * 64 + (lane >> 4) * 4;
  int c0 = n0 + wc * 64 + (lane & 15);
  #pragma unroll
  for (int m = 0; m < 4; m++)
    #pragma unroll
    for (int n = 0; n < 4; n++)
      #pragma unroll
      for (int j = 0; j < 4; j++) {
        int tr = r0 + m * 16 + j, tc = c0 + n * 16;
        size_t idx = (size_t)tr * ldc + tc;
        float v = acc[m][n][j];
        if (EPI == 1) v += resid[idx];
        C[idx] = v;
        if (EPI == 0 && tc >= 1024 && tc < 1280) {
          int s = tr >> 1, bb = tr & 1;
          int kvh = (tc - 1024) >> 6, d = (tc - 1024) & 63;
          _Float16 hh, ll; split16(v, hh, ll);
          size_t kidx = ((size_t)(bb * 4 + kvh) * 2048 + s) * 64 + d;
          kh[kidx] = hh; kl[kidx] = ll;
        }
      }
}

// ---------------- Flash attention: gload staging of pre-split K / V^T, XOR-swizzled ----------
__global__ __launch_bounds__(256) void attn2(const float* __restrict__ qkv,
    const _Float16* __restrict__ khg, const _Float16* __restrict__ klg,
    const _Float16* __restrict__ vhg, const _Float16* __restrict__ vlg,
    _Float16* __restrict__ aoh, _Float16* __restrict__ aol)
{
  __shared__ _Float16 KhS[4096], KlS[4096], VhS[4096], VlS[4096];
  __shared__ _Float16 Ph[64][72], Pl[64][72];
  int bh = blockIdx.x;
  int qt = gridDim.y - 1 - blockIdx.y;    // LPT: longest (largest qt) dispatched first
  int h = bh >> 1, b = bh & 1, kvh = h >> 2, bkv = b * 4 + kvh;
  int q0 = qt * 64;
  int tid = threadIdx.x, lane = tid & 63, w = tid >> 6;
  int rr = lane & 15, ko = (lane >> 4) * 8;
  const int xo8 = (rr & 7) << 3;
  int qrow = q0 + w * 16 + rr;
  const float* qp = qkv + (size_t)(qrow * 2 + b) * QKVN + h * 64;
  f16x8 qh[2], ql[2];
  #pragma unroll
  for (int kk = 0; kk < 2; kk++) {
    const float4* p = (const float4*)(qp + kk * 32 + ko);
    float4 v0 = p[0], v1 = p[1];
    float tq[8] = {v0.x, v0.y, v0.z, v0.w, v1.x, v1.y, v1.z, v1.w};
    f16x8 hv, lv;
    #pragma unroll
    for (int q = 0; q < 8; q++) { _Float16 hh, ll; split16(tq[q], hh, ll); hv[q] = hh; lv[q] = ll; }
    qh[kk] = hv; ql[kk] = lv;
  }
  const _Float16 *pk[2][2], *pv[2][2];
  int ldsb[2];
  #pragma unroll
  for (int i = 0; i < 2; i++) {
    int E = i * 2048 + w * 512 + lane * 8;
    int r = E >> 6, cc = E & 63;
    int cs = cc ^ ((r & 7) << 3);
    pk[i][0] = khg + ((size_t)bkv * 2048 + r) * 64 + cs;
    pk[i][1] = klg + ((size_t)bkv * 2048 + r) * 64 + cs;
    pv[i][0] = vhg + ((size_t)bkv * 64 + r) * 2048 + cs;
    pv[i][1] = vlg + ((size_t)bkv * 64 + r) * 2048 + cs;
    ldsb[i] = i * 2048 + w * 512;
  }
  f32x4 o[4] = {};
  float mo[4] = {-1e30f, -1e30f, -1e30f, -1e30f};
  float lo[4] = {0.f, 0.f, 0.f, 0.f};
  for (int ks = 0; ks <= q0; ks += 64) {
    __syncthreads();
    #pragma unroll
    for (int i = 0; i < 2; i++) {
      gload16(pk[i][0] + (size_t)ks * 64, &KhS[ldsb[i]]);
      gload16(pk[i][1] + (size_t)ks * 64, &KlS[ldsb[i]]);
      gload16(pv[i][0] + ks, &VhS[ldsb[i]]);
      gload16(pv[i][1] + ks, &VlS[ldsb[i]]);
    }
    __syncthreads();
    f32x4 s[4] = {};
    __builtin_amdgcn_s_setprio(1);
    #pragma unroll
    for (int n = 0; n < 4; n++)
      #pragma unroll
      for (int kk = 0; kk < 2; kk++) {
        int ro = (n * 16 + rr) * 64 + ((kk * 32 + ko) ^ xo8);
        f16x8 kbh = *(const f16x8*)&KhS[ro];
        f16x8 kbl = *(const f16x8*)&KlS[ro];
        s[n] = mfma16(qh[kk], kbh, s[n]);
        s[n] = mfma16(qh[kk], kbl, s[n]);
        s[n] = mfma16(ql[kk], kbh, s[n]);
      }
    __builtin_amdgcn_s_setprio(0);
    bool diag = (ks == q0);
    int myrow = q0 + w * 16 + (lane >> 4) * 4;
    #pragma unroll
    for (int n = 0; n < 4; n++)
      #pragma unroll
      for (int j = 0; j < 4; j++) {
        float v = s[n][j] * 0.125f;
        if (diag && (ks + n * 16 + rr) > (myrow + j)) v = -1e30f;
        s[n][j] = v;
      }
    float mt[4];
    #pragma unroll
    for (int j = 0; j < 4; j++) mt[j] = fmaxf(fmaxf(s[0][j], s[1][j]), fmaxf(s[2][j], s[3][j]));
    #pragma unroll
    for (int msk = 1; msk < 16; msk <<= 1)
      #pragma unroll
      for (int j = 0; j < 4; j++) mt[j] = fmaxf(mt[j], __shfl_xor(mt[j], msk, 64));
    float pvv[4][4], rsum[4];
    #pragma unroll
    for (int j = 0; j < 4; j++) {
      float mn = fmaxf(mo[j], mt[j]);
      float al = expf(mo[j] - mn);
      mo[j] = mn;
      rsum[j] = 0.f;
      #pragma unroll
      for (int n = 0; n < 4; n++) { float pp = expf(s[n][j] - mn); pvv[n][j] = pp; rsum[j] += pp; }
      lo[j] *= al;
      #pragma unroll
      for (int n = 0; n < 4; n++) o[n][j] *= al;
    }
    #pragma unroll
    for (int msk = 1; msk < 16; msk <<= 1)
      #pragma unroll
      for (int j = 0; j < 4; j++) rsum[j] += __shfl_xor(rsum[j], msk, 64);
    #pragma unroll
    for (int j = 0; j < 4; j++) lo[j] += rsum[j];
    int prow = w * 16 + (lane >> 4) * 4;
    #pragma unroll
    for (int n = 0; n < 4; n++)
      #pragma unroll
      for (int j = 0; j < 4; j++) {
        _Float16 hh, ll; split16(pvv[n][j], hh, ll);
        Ph[prow + j][n * 16 + rr] = hh;
        Pl[prow + j][n * 16 + rr] = ll;
      }
    __builtin_amdgcn_s_setprio(1);
    #pragma unroll
    for (int kk = 0; kk < 2; kk++) {
      f16x8 pah = *(const f16x8*)&Ph[w * 16 + rr][kk * 32 + ko];
      f16x8 pal = *(const f16x8*)&Pl[w * 16 + rr][kk * 32 + ko];
      #pragma unroll
      for (int dn = 0; dn < 4; dn++) {
        int ro = (dn * 16 + rr) * 64 + ((kk * 32 + ko) ^ xo8);
        f16x8 vbh = *(const f16x8*)&VhS[ro];
        f16x8 vbl = *(const f16x8*)&VlS[ro];
        o[dn] = mfma16(pah, vbh, o[dn]);
        o[dn] = mfma16(pah, vbl, o[dn]);
        o[dn] = mfma16(pal, vbh, o[dn]);
      }
    }
    __builtin_amdgcn_s_setprio(0);
  }
  float inv[4];
  #pragma unroll
  for (int j = 0; j < 4; j++) inv[j] = 1.0f / lo[j];
  int orow = q0 + w * 16 + (lane >> 4) * 4;
  int ocol = h * 64 + rr;
  #pragma unroll
  for (int dn = 0; dn < 4; dn++)
    #pragma unroll
    for (int j = 0; j < 4; j++) {
      float v = o[dn][j] * inv[j];
      _Float16 hh, ll; split16(v, hh, ll);
      size_t idx = (size_t)((orow + j) * 2 + b) * HH + ocol + dn * 16;
      aoh[idx] = hh; aol[idx] = ll;
    }
}

// ---------------- Router: f32 logits, softmax, top-2, scatter to per-expert lists ----------------
__global__ __launch_bounds__(256) void router_kernel(const float* __restrict__ x,
    const float* __restrict__ rw, int* __restrict__ list, float* __restrict__ listp,
    int* __restrict__ cnt)
{
  __shared__ float rws[HH * 8];
  int tid = threadIdx.x;
  for (int i = tid; i < HH * 8; i += 256) rws[i] = rw[i];
  __syncthreads();
  int t = blockIdx.x * 4 + (tid >> 6);
  int lane = tid & 63;
  const float* xp = x + (size_t)t * HH;
  float acc[8] = {};
  for (int i = lane; i < HH; i += 64) {
    float xv = xp[i];
    #pragma unroll
    for (int e = 0; e < 8; e++) acc[e] += xv * rws[i * 8 + e];
  }
  #pragma unroll
  for (int e = 0; e < 8; e++)
    #pragma unroll
    for (int m = 1; m < 64; m <<= 1) acc[e] += __shfl_xor(acc[e], m, 64);
  if (lane == 0) {
    float mx = acc[0];
    #pragma unroll
    for (int e = 1; e < 8; e++) mx = fmaxf(mx, acc[e]);
    float p[8], sum = 0.f;
    #pragma unroll
    for (int e = 0; e < 8; e++) { p[e] = expf(acc[e] - mx); sum += p[e]; }
    float inv = 1.0f / sum;
    int i1 = 0; float v1 = acc[0];
    #pragma unroll
    for (int e = 1; e < 8; e++) if (acc[e] > v1) { v1 = acc[e]; i1 = e; }
    int i2 = -1; float v2 = -3.4e38f;
    #pragma unroll
    for (int e = 0; e < 8; e++) if (e != i1 && acc[e] > v2) { v2 = acc[e]; i2 = e; }
    int pos1 = atomicAdd(&cnt[i1], 1);
    list[i1 * TT + pos1] = t; listp[i1 * TT + pos1] = p[i1] * inv;
    int pos2 = atomicAdd(&cnt[i2], 1);
    list[i2 * TT + pos2] = t; listp[i2 * TT + pos2] = p[i2] * inv;
  }
}

// ======== MoE GEMMs: 256x256 tile, 8 waves, BK=32, FOUR LDS bufs (128KB), depth-3 prefetch ====
// Per-wave output 128x64 (wr=w>>2, wc=w&3), acc[8][4]. 4 loads/thread/K-tile.
// Prologue stages tiles 0,1,2 into bufs 0,1,2. Iter t: issue tile t+3 into buf (t+3)&3
// (that buf's previous tile was last read at iter t-1, fenced by lgkmcnt(0)+barrier) ->
// vmcnt(12) [3 newest tiles in flight; tile t landed] -> barrier -> 12 ds_read + 32 MFMA ->
// lgkmcnt(0) -> barrier. Never drains vmcnt to 0 mid-loop.

// moe1: hidden = gelu(gather(xbf) @ w1T[e]^T). 1D grid: e=id&7 (XCD-pinned), mx=(id>>3)&15, nx=id>>7.
__global__ __launch_bounds__(512, 1) void moe1_c4(const short* __restrict__ xbf,
    const short* __restrict__ w1T, const int* __restrict__ list,
    const int* __restrict__ cnt, short* __restrict__ hidden)
{
  __shared__ short A4[4][8192], B4[4][8192];   // [256][32] each, 128 KB total
  int id = blockIdx.x;
  int e = id & 7;
  int inner = id >> 3;
  int mx = inner & 15, nx = inner >> 4;
  int ce = cnt[e];
  int m0 = mx * 256;
  if (m0 >= ce) return;                        // block-uniform, before any barrier
  int n0 = nx * 256;
  int off = 0;
  #pragma unroll
  for (int i = 0; i < 8; i++) if (i < e) off += cnt[i];
  const int tid = threadIdx.x, lane = tid & 63, w = tid >> 6;
  const int wr = w >> 2, wc = w & 3;
  f32x4 acc[8][4] = {};
  const short *pa[2], *pb[2];
  int lof[2];
  #pragma unroll
  for (int q = 0; q < 2; q++) {
    int E = q * 4096 + w * 512 + lane * 8;     // element in [256][32]
    int r = E >> 5, c = E & 31;
    int cs = c ^ ((r & 3) << 3);
    int apos = m0 + r; if (apos > ce - 1) apos = ce - 1;
    int tok = list[e * TT + apos];
    pa[q] = xbf + (size_t)tok * HH + cs;
    pb[q] = w1T + ((size_t)e * FF + n0 + r) * HH + cs;
    lof[q] = E;
  }
  const int rr = lane & 15, ko = (lane >> 4) * 8;
  const int koX = ko ^ ((rr & 3) << 3);
  const int T = HH / 32;                       // 32
  // prologue: stage tiles 0,1,2
  #pragma unroll
  for (int t0 = 0; t0 < 3; t0++)
    #pragma unroll
    for (int q = 0; q < 2; q++) {
      gload16(pa[q] + t0 * 32, &A4[t0][lof[q]]);
      gload16(pb[q] + t0 * 32, &B4[t0][lof[q]]);
    }
  int cb = 0;
  for (int t = 0; t < T; t++) {
    if (t + 3 < T) {
      int k0 = (t + 3) * 32;
      int nb = cb + 3; if (nb >= 4) nb -= 4;
      #pragma unroll
      for (int q = 0; q < 2; q++) {
        gload16(pa[q] + k0, &A4[nb][lof[q]]);
        gload16(pb[q] + k0, &B4[nb][lof[q]]);
      }
      asm volatile("s_waitcnt vmcnt(12)" ::: "memory");
    } else if (t + 2 < T) {
      asm volatile("s_waitcnt vmcnt(8)" ::: "memory");
    } else if (t + 1 < T) {
      asm volatile("s_waitcnt vmcnt(4)" ::: "memory");
    } else {
      asm volatile("s_waitcnt vmcnt(0)" ::: "memory");
    }
    __builtin_amdgcn_s_barrier();
    __builtin_amdgcn_sched_barrier(0);
    bf16x8 fa[8], fb[4];
    #pragma unroll
    for (int m = 0; m < 8; m++) fa[m] = *(const bf16x8*)&A4[cb][(wr * 128 + m * 16 + rr) * 32 + koX];
    #pragma unroll
    for (int n = 0; n < 4; n++) fb[n] = *(const bf16x8*)&B4[cb][(wc * 64 + n * 16 + rr) * 32 + koX];
    __builtin_amdgcn_s_setprio(1);
    #pragma unroll
    for (int m = 0; m < 8; m++)
      #pragma unroll
      for (int n = 0; n < 4; n++) acc[m][n] = mfmabf(fa[m], fb[n], acc[m][n]);
    __builtin_amdgcn_s_setprio(0);
    asm volatile("s_waitcnt lgkmcnt(0)" ::: "memory");
    __builtin_amdgcn_s_barrier();
    __builtin_amdgcn_sched_barrier(0);
    cb += 1; if (cb >= 4) cb -= 4;
  }
  int p0 = m0 + wr * 128 + (lane >> 4) * 4;
  int c0 = n0 + wc * 64 + (lane & 15);
  #pragma unroll
  for (int m = 0; m < 8; m++)
    #pragma unroll
    for (int n = 0; n < 4; n++)
      #pragma unroll
      for (int j = 0; j < 4; j++) {
        int pos = p0 + m * 16 + j;
        if (pos < ce) {
          float v = fast_gelu(acc[m][n][j]);
          hidden[(size_t)(off + pos) * FF + c0 + n * 16] = f2bf(v);
        }
      }
}

// moe2: out[tok] += p * (hidden @ w2T[e]^T), split-K x2, atomic epilogue.
// id: e=id&7; r=id>>3: mx=r&15, nx=(r>>4)&3, ksp=r>>6.
__global__ __launch_bounds__(512, 1) void moe2_c4(const short* __restrict__ hidden,
    const short* __restrict__ w2T, const int* __restrict__ list,
    const float* __restrict__ listp, const int* __restrict__ cnt,
    float* __restrict__ outp)
{
  __shared__ short A4[4][8192], B4[4][8192];
  int id = blockIdx.x;
  int e = id & 7;
  int r_ = id >> 3;
  int mx = r_ & 15, nx = (r_ >> 4) & 3, ksp = r_ >> 6;
  int ce = cnt[e];
  int m0 = mx * 256;
  if (m0 >= ce) return;
  int n0 = nx * 256;
  int kbase = ksp * (FF / 2);
  int off = 0;
  #pragma unroll
  for (int i = 0; i < 8; i++) if (i < e) off += cnt[i];
  const int tid = threadIdx.x, lane = tid & 63, w = tid >> 6;
  const int wr = w >> 2, wc = w & 3;
  f32x4 acc[8][4] = {};
  const short *pa[2], *pb[2];
  int lof[2];
  #pragma unroll
  for (int q = 0; q < 2; q++) {
    int E = q * 4096 + w * 512 + lane * 8;
    int r = E >> 5, c = E & 31;
    int cs = c ^ ((r & 3) << 3);
    int apos = m0 + r; if (apos > ce - 1) apos = ce - 1;
    pa[q] = hidden + ((size_t)off + apos) * FF + kbase + cs;
    pb[q] = w2T + ((size_t)e * HH + n0 + r) * FF + kbase + cs;
    lof[q] = E;
  }
  const int rr = lane & 15, ko = (lane >> 4) * 8;
  const int koX = ko ^ ((rr & 3) << 3);
  const int T = (FF / 2) / 32;                 // 64
  #pragma unroll
  for (int t0 = 0; t0 < 3; t0++)
    #pragma unroll
    for (int q = 0; q < 2; q++) {
      gload16(pa[q] + t0 * 32, &A4[t0][lof[q]]);
      gload16(pb[q] + t0 * 32, &B4[t0][lof[q]]);
    }
  int cb = 0;
  for (int t = 0; t < T; t++) {
    if (t + 3 < T) {
      int k0 = (t + 3) * 32;
      int nb = cb + 3; if (nb >= 4) nb -= 4;
      #pragma unroll
      for (int q = 0; q < 2; q++) {
        gload16(pa[q] + k0, &A4[nb][lof[q]]);
        gload16(pb[q] + k0, &B4[nb][lof[q]]);
      }
      asm volatile("s_waitcnt vmcnt(12)" ::: "memory");
    } else if (t + 2 < T) {
      asm volatile("s_waitcnt vmcnt(8)" ::: "memory");
    } else if (t + 1 < T) {
      asm volatile("s_waitcnt vmcnt(4)" ::: "memory");
    } else {
      asm volatile("s_waitcnt vmcnt(0)" ::: "memory");
    }
    __builtin_amdgcn_s_barrier();
    __builtin_amdgcn_sched_barrier(0);
    bf16x8 fa[8], fb[4];
    #pragma unroll
    for (int m = 0; m < 8; m++) fa[m] = *(const bf16x8*)&A4[cb][(wr * 128 + m * 16 + rr) * 32 + koX];
    #pragma unroll
    for (int n = 0; n < 4; n++) fb[n] = *(const bf16x8*)&B4[cb][(wc * 64 + n * 16 + rr) * 32 + koX];
    __builtin_amdgcn_s_setprio(1);
    #pragma unroll
    for (int m = 0; m < 8; m++)
      #pragma unroll
      for (int n = 0; n < 4; n++) acc[m][n] = mfmabf(fa[m], fb[n], acc[m][n]);
    __builtin_amdgcn_s_setprio(0);
    asm volatile("s_waitcnt lgkmcnt(0)" ::: "memory");
    __builtin_amdgcn_s_barrier();
    __builtin_amdgcn_sched_barrier(0);
    cb += 1; if (cb >= 4) cb -= 4;
  }
  int p0 = m0 + wr * 128 + (lane >> 4) * 4;
  int c0 = n0 + wc * 64 + (lane & 15);
  #pragma unroll
  for (int m = 0; m < 8; m++)
    #pragma unroll
    for (int j = 0; j < 4; j++) {
      int pos = p0 + m * 16 + j;
      if (pos < ce) {
        int tk = list[e * TT + pos];
        float pw = listp[e * TT + pos];
        #pragma unroll
        for (int n = 0; n < 4; n++)
          atomicAdd(&outp[(size_t)tk * HH + c0 + n * 16], pw * acc[m][n][j]);
      }
    }
}

// ---------------- fallback MoE kernels (round-1, known-good; used when ws is small) -----------
__global__ __launch_bounds__(256) void moe_gemm1(const float* __restrict__ x,
    const float* __restrict__ w1, const int* __restrict__ list,
    const int* __restrict__ cnt, short* __restrict__ hidden, int e)
{
  int ce = cnt[e];
  int m0 = blockIdx.y * 128;
  if (m0 >= ce) return;
  int n0 = blockIdx.x * 128;
  __shared__ short As[128][40], Bs[128][40];
  int tid = threadIdx.x, lane = tid & 63, w = tid >> 6, wr = w >> 1, wc = w & 1;
  f32x4 acc[4][4] = {};
  int arow = tid >> 1, akh = (tid & 1) * 16;
  int apos = m0 + arow;
  int tok = list[(size_t)e * TT + (apos < ce ? apos : 0)];
  const float* ap = x + (size_t)tok * HH + akh;
  int bn = tid & 127, bkh = (tid >> 7) * 16;
  const float* bp = w1 + (size_t)e * HH * FF + (size_t)bkh * FF + n0 + bn;
  for (int k0 = 0; k0 < HH; k0 += 32) {
    __syncthreads();
    {
      const float4* p = (const float4*)(ap + k0);
      bf16x8 s0, s1;
      #pragma unroll
      for (int q = 0; q < 2; q++) { float4 v = p[q]; s0[q*4] = f2bf(v.x); s0[q*4+1] = f2bf(v.y); s0[q*4+2] = f2bf(v.z); s0[q*4+3] = f2bf(v.w); }
      #pragma unroll
      for (int q = 0; q < 2; q++) { float4 v = p[q+2]; s1[q*4] = f2bf(v.x); s1[q*4+1] = f2bf(v.y); s1[q*4+2] = f2bf(v.z); s1[q*4+3] = f2bf(v.w); }
      *(bf16x8*)&As[arow][akh] = s0; *(bf16x8*)&As[arow][akh+8] = s1;
    }
    {
      const float* p = bp + (size_t)k0 * FF;
      bf16x8 s0, s1;
      #pragma unroll
      for (int q = 0; q < 8; q++) s0[q] = f2bf(p[(size_t)q * FF]);
      #pragma unroll
      for (int q = 0; q < 8; q++) s1[q] = f2bf(p[(size_t)(q+8) * FF]);
      *(bf16x8*)&Bs[bn][bkh] = s0; *(bf16x8*)&Bs[bn][bkh+8] = s1;
    }
    __syncthreads();
    int rr = lane & 15, ko = (lane >> 4) * 8;
    bf16x8 fa[4], fb[4];
    #pragma unroll
    for (int m = 0; m < 4; m++) fa[m] = *(bf16x8*)&As[wr*64 + m*16 + rr][ko];
    #pragma unroll
    for (int n = 0; n < 4; n++) fb[n] = *(bf16x8*)&Bs[wc*64 + n*16 + rr][ko];
    #pragma unroll
    for (int m = 0; m < 4; m++)
      #pragma unroll
      for (int n = 0; n < 4; n++) acc[m][n] = mfmabf(fa[m], fb[n], acc[m][n]);
  }
  int p0 = m0 + wr*64 + (lane >> 4) * 4;
  int c0 = n0 + wc*64 + (lane & 15);
  #pragma unroll
  for (int m = 0; m < 4; m++)
    #pragma unroll
    for (int n = 0; n < 4; n++)
      #pragma unroll
      for (int j = 0; j < 4; j++) {
        int pos = p0 + m*16 + j;
        if (pos < ce) {
          float v = acc[m][n][j];
          v = 0.5f * v * (1.0f + erff(v * 0.70710678f));
          hidden[(size_t)pos * FF + c0 + n*16] = f2bf(v);
        }
      }
}

__global__ __launch_bounds__(256) void moe_gemm2(const short* __restrict__ hidden,
    const float* __restrict__ w2, const int* __restrict__ list,
    const float* __restrict__ listp, const int* __restrict__ cnt,
    float* __restrict__ outp, int e)
{
  int ce = cnt[e];
  int m0 = blockIdx.y * 128;
  if (m0 >= ce) return;
  int n0 = blockIdx.x * 128;
  __shared__ short As[128][40], Bs[128][40];
  int tid = threadIdx.x, lane = tid & 63, w = tid >> 6, wr = w >> 1, wc = w & 1;
  f32x4 acc[4][4] = {};
  int arow = tid >> 1, akh = (tid & 1) * 16;
  int apos = m0 + arow;
  const short* ap = hidden + (size_t)(apos < ce ? apos : 0) * FF + akh;
  int bn = tid & 127, bkh = (tid >> 7) * 16;
  const float* bp = w2 + (size_t)e * FF * HH + (size_t)bkh * HH + n0 + bn;
  for (int k0 = 0; k0 < FF; k0 += 32) {
    __syncthreads();
    {
      const int4* p = (const int4*)(ap + k0);
      int4 a0 = p[0], a1 = p[1];
      *(int4*)&As[arow][akh]   = a0;
      *(int4*)&As[arow][akh+8] = a1;
    }
    {
      const float* p = bp + (size_t)k0 * HH;
      bf16x8 s0, s1;
      #pragma unroll
      for (int q = 0; q < 8; q++) s0[q] = f2bf(p[(size_t)q * HH]);
      #pragma unroll
      for (int q = 0; q < 8; q++) s1[q] = f2bf(p[(size_t)(q+8) * HH]);
      *(bf16x8*)&Bs[bn][bkh] = s0; *(bf16x8*)&Bs[bn][bkh+8] = s1;
    }
    __syncthreads();
    int rr = lane & 15, ko = (lane >> 4) * 8;
    bf16x8 fa[4], fb[4];
    #pragma unroll
    for (int m = 0; m < 4; m++) fa[m] = *(bf16x8*)&As[wr*64 + m*16 + rr][ko];
    #pragma unroll
    for (int n = 0; n < 4; n++) fb[n] = *(bf16x8*)&Bs[wc*64 + n*16 + rr][ko];
    #pragma unroll
    for (int m = 0; m < 4; m++)
      #pragma unroll
      for (int n = 0; n < 4; n++) acc[m][n] = mfmabf(fa[m], fb[n], acc[m][n]);
  }
  int p0 = m0 + wr*64 + (lane >> 4) * 4;
  int c0 = n0 + wc*64 + (lane & 15);
  #pragma unroll
  for (int m = 0; m < 4; m++)
    #pragma unroll
    for (int j = 0; j < 4; j++) {
      int pos = p0 + m*16 + j;
      if (pos < ce) {
        int tk = list[(size_t)e * TT + pos];
        float pw = listp[(size_t)e * TT + pos];
        #pragma unroll
        for (int n = 0; n < 4; n++)
          atomicAdd(&outp[(size_t)tk * HH + c0 + n*16], pw * acc[m][n][j]);
      }
    }
}

extern "C" void kernel_launch(void* const* d_in, const int* in_sizes, int n_in,
                              void* d_out, int out_size, void* d_ws, size_t ws_size,
                              hipStream_t stream)
{
  const float* hs      = (const float*)d_in[0];
  const float* ln1w    = (const float*)d_in[1];
  const float* ln1b    = (const float*)d_in[2];
  const float* ln2w    = (const float*)d_in[3];
  const float* ln2b    = (const float*)d_in[4];
  const float* qkvw    = (const float*)d_in[5];
  const float* projw   = (const float*)d_in[6];
  const float* routerw = (const float*)d_in[7];
  const float* w1      = (const float*)d_in[8];
  const float* w2      = (const float*)d_in[9];
  float* out = (float*)d_out;

  const size_t MB = 1024 * 1024;
  char* wsb = (char*)d_ws;
  bool full = ws_size >= 153 * MB;

  float*    qkvbuf = (float*)wsb;
  _Float16* khb    = (_Float16*)(wsb + 24 * MB);
  _Float16* klb    = (_Float16*)(wsb + 26 * MB);
  _Float16* vhb    = (_Float16*)(wsb + 28 * MB);
  _Float16* vlb    = (_Float16*)(wsb + 30 * MB);
  short*    hidden = (short*)wsb;
  size_t r2 = full ? 64 * MB : 32 * MB;
  _Float16* ln1h = (_Float16*)(wsb + r2);
  _Float16* ln1l = (_Float16*)(wsb + r2 + 8 * MB);
  _Float16* aohb = ln1h;
  _Float16* aolb = ln1l;
  float*    xbuf = (float*)(wsb + r2);
  short*    xbf  = (short*)(wsb + r2 + 16 * MB);
  size_t r3 = full ? 88 * MB : 56 * MB;
  _Float16* qkvwTh  = (_Float16*)(wsb + r3);
  _Float16* qkvwTl  = (_Float16*)(wsb + r3 + 3 * MB);
  _Float16* projwTh = (_Float16*)(wsb + r3 + 6 * MB);
  _Float16* projwTl = (_Float16*)(wsb + r3 + 8 * MB);
  short*    w1T     = (short*)(wsb + r3);
  short*    w2T     = (short*)(wsb + r3);
  size_t r4 = full ? 152 * MB : 66 * MB;
  int*   list  = (int*)(wsb + r4);
  float* listp = (float*)(wsb + r4 + 128 * 1024);
  int*   cnt   = (int*)(wsb + r4 + 256 * 1024);

  zero_cnt<<<1, 64, 0, stream>>>(cnt);
  wconv_split<<<dim3(QKVN / 64, HH / 64), 256, 0, stream>>>(qkvw, qkvwTh, qkvwTl, HH, QKVN);
  wconv_split<<<dim3(HH / 64, HH / 64), 256, 0, stream>>>(projw, projwTh, projwTl, HH, HH);
  ln_split<0><<<TT, 256, 0, stream>>>(hs, ln1w, ln1b, ln1h, ln1l, nullptr, nullptr);
  gemm_split2<0><<<dim3(QKVN / 128, TT / 128), 256, 0, stream>>>(
      ln1h, ln1l, qkvwTh, qkvwTl, HH, qkvbuf, QKVN, nullptr, khb, klb);
  vtrans<<<dim3(8, 32), 256, 0, stream>>>(qkvbuf, vhb, vlb);
  attn2<<<dim3(32, 32), 256, 0, stream>>>(qkvbuf, khb, klb, vhb, vlb, aohb, aolb);
  gemm_split2<1><<<dim3(HH / 128, TT / 128), 256, 0, stream>>>(
      aohb, aolb, projwTh, projwTl, HH, out, HH, hs, nullptr, nullptr);
  ln_split<1><<<TT, 256, 0, stream>>>(out, ln2w, ln2b, nullptr, nullptr, xbuf, xbf);
  router_kernel<<<TT / 4, 256, 0, stream>>>(xbuf, routerw, list, listp, cnt);
  if (full) {
    wconv_bf<<<dim3(FF / 64, HH / 64, 8), 256, 0, stream>>>(w1, w1T, HH, FF);
    moe1_c4<<<8 * 16 * 16, 512, 0, stream>>>(xbf, w1T, list, cnt, hidden);
    wconv_bf<<<dim3(HH / 64, FF / 64, 8), 256, 0, stream>>>(w2, w2T, FF, HH);
    moe2_c4<<<8 * 16 * 4 * 2, 512, 0, stream>>>(hidden, w2T, list, listp, cnt, out);
  } else {
    for (int e = 0; e < 8; e++) {
      moe_gemm1<<<dim3(FF / 128, TT / 128), 256, 0, stream>>>(xbuf, w1, list, cnt, hidden, e);
      moe_gemm2<<<dim3(HH / 128, TT / 128), 256, 0, stream>>>(hidden, w2, list, listp, cnt, out, e);
    }
  }
}

// Round 12
// 684.126 us; speedup vs baseline: 1.1566x; 1.1566x over previous
//
#include <hip/hip_runtime.h>
#include <hip/hip_bf16.h>

// Problem constants (S=2048, B=2, H=1024, NH=16, NKV=4, HD=64, E=8, K=2, F=4096)
constexpr int TT   = 4096;   // S*B tokens
constexpr int HH   = 1024;
constexpr int QKVN = 1536;
constexpr int FF   = 4096;

using f16x8  = __attribute__((ext_vector_type(8))) _Float16;
using f16x4  = __attribute__((ext_vector_type(4))) _Float16;
using bf16x8 = __attribute__((ext_vector_type(8))) short;
using s16x4  = __attribute__((ext_vector_type(4))) short;
using f32x4  = __attribute__((ext_vector_type(4))) float;

static __device__ __forceinline__ f32x4 mfma16(f16x8 a, f16x8 b, f32x4 c) {
  return __builtin_amdgcn_mfma_f32_16x16x32_f16(a, b, c, 0, 0, 0);
}
static __device__ __forceinline__ f32x4 mfmabf(bf16x8 a, bf16x8 b, f32x4 c) {
  return __builtin_amdgcn_mfma_f32_16x16x32_bf16(a, b, c, 0, 0, 0);
}
static __device__ __forceinline__ short f2bf(float f) {
  union { float f; unsigned u; } v; v.f = f;
  unsigned r = v.u + 0x7fffu + ((v.u >> 16) & 1u);
  return (short)(r >> 16);
}
static __device__ __forceinline__ void split16(float f, _Float16 &h, _Float16 &l) {
  _Float16 hh = (_Float16)f; h = hh; l = (_Float16)(f - (float)hh);
}
// fast tanh-gelu (max |diff| vs exact-gelu ~3e-3; hidden is bf16 anyway)
static __device__ __forceinline__ float fast_gelu(float x) {
  float u = 0.7978845608f * (x + 0.044715f * x * x * x);
  float a = __expf(-2.0f * fabsf(u));
  float t = (1.0f - a) * __builtin_amdgcn_rcpf(1.0f + a);
  t = copysignf(t, u);
  return 0.5f * x * (1.0f + t);
}
// async global->LDS, 16B per lane. LDS ptr must be wave-uniform; global ptr is per-lane.
static __device__ __forceinline__ void gload16(const void* g, void* l) {
  __builtin_amdgcn_global_load_lds((__attribute__((address_space(1))) void*)(g),
                                   (__attribute__((address_space(3))) void*)(l), 16, 0, 0);
}

__global__ void zero_cnt(int* cnt) { if (threadIdx.x < 8) cnt[threadIdx.x] = 0; }

// ---------------- weight transpose + fp16 hi/lo split: W[K][N] f32 -> out[N][K] f16 x2 ----------
__global__ __launch_bounds__(256) void wconv_split(const float* __restrict__ W,
    _Float16* __restrict__ oh, _Float16* __restrict__ ol, int K, int N)
{
  __shared__ float ts[64][68];
  int n0 = blockIdx.x * 64, k0 = blockIdx.y * 64, t = threadIdx.x;
  #pragma unroll
  for (int it = 0; it < 4; it++) {
    int el = it * 1024 + t * 4; int r = el >> 6, c = el & 63;
    float4 v = *(const float4*)&W[(size_t)(k0 + r) * N + n0 + c];
    *(float4*)&ts[r][c] = v;
  }
  __syncthreads();
  #pragma unroll
  for (int it = 0; it < 4; it++) {
    int el = it * 1024 + t * 4; int nr = el >> 6, kc = el & 63;
    f16x4 hv, lv;
    #pragma unroll
    for (int q = 0; q < 4; q++) { _Float16 hh, ll; split16(ts[kc + q][nr], hh, ll); hv[q] = hh; lv[q] = ll; }
    size_t o = (size_t)(n0 + nr) * K + k0 + kc;
    *(f16x4*)&oh[o] = hv; *(f16x4*)&ol[o] = lv;
  }
}

// ---------------- weight transpose to bf16 (batched over experts via z): W[z][K][N] -> out[z][N][K]
__global__ __launch_bounds__(256) void wconv_bf(const float* __restrict__ W,
    short* __restrict__ o, int K, int N)
{
  __shared__ float ts[64][68];
  const float* Wz = W + (size_t)blockIdx.z * K * N;
  short* oz = o + (size_t)blockIdx.z * K * N;
  int n0 = blockIdx.x * 64, k0 = blockIdx.y * 64, t = threadIdx.x;
  #pragma unroll
  for (int it = 0; it < 4; it++) {
    int el = it * 1024 + t * 4; int r = el >> 6, c = el & 63;
    float4 v = *(const float4*)&Wz[(size_t)(k0 + r) * N + n0 + c];
    *(float4*)&ts[r][c] = v;
  }
  __syncthreads();
  #pragma unroll
  for (int it = 0; it < 4; it++) {
    int el = it * 1024 + t * 4; int nr = el >> 6, kc = el & 63;
    s16x4 bv;
    #pragma unroll
    for (int q = 0; q < 4; q++) bv[q] = f2bf(ts[kc + q][nr]);
    *(s16x4*)&oz[(size_t)(n0 + nr) * K + k0 + kc] = bv;
  }
}

// ---------------- V transpose: qkv f32 V-cols -> vt[bkv][d][s] f16 hi/lo ----------------
__global__ __launch_bounds__(256) void vtrans(const float* __restrict__ qkv,
    _Float16* __restrict__ vh, _Float16* __restrict__ vl)
{
  __shared__ float ts[64][68];
  int bkv = blockIdx.x, b = bkv >> 2, kvh = bkv & 3;
  int s0 = blockIdx.y * 64, t = threadIdx.x;
  #pragma unroll
  for (int it = 0; it < 4; it++) {
    int el = it * 1024 + t * 4; int r = el >> 6, c = el & 63;
    float4 v = *(const float4*)&qkv[(size_t)((s0 + r) * 2 + b) * QKVN + 1280 + kvh * 64 + c];
    *(float4*)&ts[r][c] = v;
  }
  __syncthreads();
  #pragma unroll
  for (int it = 0; it < 4; it++) {
    int el = it * 1024 + t * 4; int d = el >> 6, sc = el & 63;
    f16x4 hv, lv;
    #pragma unroll
    for (int q = 0; q < 4; q++) { _Float16 hh, ll; split16(ts[sc + q][d], hh, ll); hv[q] = hh; lv[q] = ll; }
    size_t o = ((size_t)bkv * 64 + d) * 2048 + s0 + sc;
    *(f16x4*)&vh[o] = hv; *(f16x4*)&vl[o] = lv;
  }
}

// ---------------- LayerNorm, f32 math. MODE 0: emit fp16 hi/lo. MODE 1: emit f32 + bf16 -------
template<int MODE>
__global__ __launch_bounds__(256) void ln_split(const float* __restrict__ in,
    const float* __restrict__ wt, const float* __restrict__ bs,
    _Float16* __restrict__ oh, _Float16* __restrict__ ol,
    float* __restrict__ xo, short* __restrict__ xbo)
{
  int row = blockIdx.x, tid = threadIdx.x;
  const float4* ip = (const float4*)(in + (size_t)row * HH);
  float4 v = ip[tid];
  float s = v.x + v.y + v.z + v.w;
  #pragma unroll
  for (int m = 1; m < 64; m <<= 1) s += __shfl_xor(s, m, 64);
  __shared__ float red1[4], red2[4];
  int wid = tid >> 6;
  if ((tid & 63) == 0) red1[wid] = s;
  __syncthreads();
  float mu = (red1[0] + red1[1] + red1[2] + red1[3]) * (1.0f / HH);
  float4 c; c.x = v.x - mu; c.y = v.y - mu; c.z = v.z - mu; c.w = v.w - mu;
  float s2 = c.x*c.x + c.y*c.y + c.z*c.z + c.w*c.w;
  #pragma unroll
  for (int m = 1; m < 64; m <<= 1) s2 += __shfl_xor(s2, m, 64);
  if ((tid & 63) == 0) red2[wid] = s2;
  __syncthreads();
  float ve = (red2[0] + red2[1] + red2[2] + red2[3]) * (1.0f / HH) + 1e-5f;
  float rs = rsqrtf(ve);
  rs = rs * (1.5f - 0.5f * ve * rs * rs);
  float4 wv = ((const float4*)wt)[tid], bv = ((const float4*)bs)[tid];
  float o4[4];
  o4[0] = c.x * rs * wv.x + bv.x; o4[1] = c.y * rs * wv.y + bv.y;
  o4[2] = c.z * rs * wv.z + bv.z; o4[3] = c.w * rs * wv.w + bv.w;
  size_t base = (size_t)row * HH + tid * 4;
  if (MODE == 0) {
    f16x4 hv, lv;
    #pragma unroll
    for (int q = 0; q < 4; q++) { _Float16 hh, ll; split16(o4[q], hh, ll); hv[q] = hh; lv[q] = ll; }
    *(f16x4*)&oh[base] = hv; *(f16x4*)&ol[base] = lv;
  } else {
    float4 ov; ov.x = o4[0]; ov.y = o4[1]; ov.z = o4[2]; ov.w = o4[3];
    *(float4*)&xo[base] = ov;
    s16x4 bvv;
    #pragma unroll
    for (int q = 0; q < 4; q++) bvv[q] = f2bf(o4[q]);
    *(s16x4*)&xbo[base] = bvv;
  }
}

// ------- fp16-split GEMM, m97-style: global_load_lds staging, 128x128 tile, BK=32, 3-pass MFMA
template<int EPI>
__global__ __launch_bounds__(256) void gemm_split2(
    const _Float16* __restrict__ Agh, const _Float16* __restrict__ Agl,
    const _Float16* __restrict__ Bgh, const _Float16* __restrict__ Bgl,
    int K, float* __restrict__ C, int ldc, const float* __restrict__ resid,
    _Float16* __restrict__ kh, _Float16* __restrict__ kl)
{
  __shared__ _Float16 AhS[4096], AlS[4096], BhS[4096], BlS[4096];
  const int tid = threadIdx.x, lane = tid & 63, w = tid >> 6;
  const int wr = w >> 1, wc = w & 1;
  const int m0 = blockIdx.y * 128, n0 = blockIdx.x * 128;
  f32x4 acc[4][4] = {};
  const _Float16 *pah[2], *pal[2], *pbh[2], *pbl[2];
  int ldsb[2];
  #pragma unroll
  for (int i = 0; i < 2; i++) {
    int E = i * 2048 + w * 512 + lane * 8;
    int r = E >> 5, cc = E & 31;
    int cs = cc ^ ((r & 3) << 3);
    pah[i] = Agh + (size_t)(m0 + r) * K + cs;
    pal[i] = Agl + (size_t)(m0 + r) * K + cs;
    pbh[i] = Bgh + (size_t)(n0 + r) * K + cs;
    pbl[i] = Bgl + (size_t)(n0 + r) * K + cs;
    ldsb[i] = i * 2048 + w * 512;
  }
  const int rr = lane & 15, ko = (lane >> 4) * 8;
  const int xo = (rr & 3) << 3;
  for (int k0 = 0; k0 < K; k0 += 32) {
    __syncthreads();
    #pragma unroll
    for (int i = 0; i < 2; i++) {
      gload16(pah[i] + k0, &AhS[ldsb[i]]);
      gload16(pal[i] + k0, &AlS[ldsb[i]]);
      gload16(pbh[i] + k0, &BhS[ldsb[i]]);
      gload16(pbl[i] + k0, &BlS[ldsb[i]]);
    }
    __syncthreads();
    f16x8 fah[4], fal[4], fbh[4], fbl[4];
    #pragma unroll
    for (int m = 0; m < 4; m++) {
      int ro = (wr * 64 + m * 16 + rr) * 32 + (ko ^ xo);
      fah[m] = *(const f16x8*)&AhS[ro];
      fal[m] = *(const f16x8*)&AlS[ro];
    }
    #pragma unroll
    for (int n = 0; n < 4; n++) {
      int ro = (wc * 64 + n * 16 + rr) * 32 + (ko ^ xo);
      fbh[n] = *(const f16x8*)&BhS[ro];
      fbl[n] = *(const f16x8*)&BlS[ro];
    }
    #pragma unroll
    for (int m = 0; m < 4; m++)
      #pragma unroll
      for (int n = 0; n < 4; n++) {
        acc[m][n] = mfma16(fah[m], fbh[n], acc[m][n]);
        acc[m][n] = mfma16(fah[m], fbl[n], acc[m][n]);
        acc[m][n] = mfma16(fal[m], fbh[n], acc[m][n]);
      }
  }
  int r0 = m0 + wr * 64 + (lane >> 4) * 4;
  int c0 = n0 + wc * 64 + (lane & 15);
  #pragma unroll
  for (int m = 0; m < 4; m++)
    #pragma unroll
    for (int n = 0; n < 4; n++)
      #pragma unroll
      for (int j = 0; j < 4; j++) {
        int tr = r0 + m * 16 + j, tc = c0 + n * 16;
        size_t idx = (size_t)tr * ldc + tc;
        float v = acc[m][n][j];
        if (EPI == 1) v += resid[idx];
        C[idx] = v;
        if (EPI == 0 && tc >= 1024 && tc < 1280) {
          int s = tr >> 1, bb = tr & 1;
          int kvh = (tc - 1024) >> 6, d = (tc - 1024) & 63;
          _Float16 hh, ll; split16(v, hh, ll);
          size_t kidx = ((size_t)(bb * 4 + kvh) * 2048 + s) * 64 + d;
          kh[kidx] = hh; kl[kidx] = ll;
        }
      }
}

// ---------------- Flash attention: gload staging of pre-split K / V^T, XOR-swizzled ----------
__global__ __launch_bounds__(256) void attn2(const float* __restrict__ qkv,
    const _Float16* __restrict__ khg, const _Float16* __restrict__ klg,
    const _Float16* __restrict__ vhg, const _Float16* __restrict__ vlg,
    _Float16* __restrict__ aoh, _Float16* __restrict__ aol)
{
  __shared__ _Float16 KhS[4096], KlS[4096], VhS[4096], VlS[4096];
  __shared__ _Float16 Ph[64][72], Pl[64][72];
  int bh = blockIdx.x;
  int qt = gridDim.y - 1 - blockIdx.y;    // LPT: longest (largest qt) dispatched first
  int h = bh >> 1, b = bh & 1, kvh = h >> 2, bkv = b * 4 + kvh;
  int q0 = qt * 64;
  int tid = threadIdx.x, lane = tid & 63, w = tid >> 6;
  int rr = lane & 15, ko = (lane >> 4) * 8;
  const int xo8 = (rr & 7) << 3;
  int qrow = q0 + w * 16 + rr;
  const float* qp = qkv + (size_t)(qrow * 2 + b) * QKVN + h * 64;
  f16x8 qh[2], ql[2];
  #pragma unroll
  for (int kk = 0; kk < 2; kk++) {
    const float4* p = (const float4*)(qp + kk * 32 + ko);
    float4 v0 = p[0], v1 = p[1];
    float tq[8] = {v0.x, v0.y, v0.z, v0.w, v1.x, v1.y, v1.z, v1.w};
    f16x8 hv, lv;
    #pragma unroll
    for (int q = 0; q < 8; q++) { _Float16 hh, ll; split16(tq[q], hh, ll); hv[q] = hh; lv[q] = ll; }
    qh[kk] = hv; ql[kk] = lv;
  }
  const _Float16 *pk[2][2], *pv[2][2];
  int ldsb[2];
  #pragma unroll
  for (int i = 0; i < 2; i++) {
    int E = i * 2048 + w * 512 + lane * 8;
    int r = E >> 6, cc = E & 63;
    int cs = cc ^ ((r & 7) << 3);
    pk[i][0] = khg + ((size_t)bkv * 2048 + r) * 64 + cs;
    pk[i][1] = klg + ((size_t)bkv * 2048 + r) * 64 + cs;
    pv[i][0] = vhg + ((size_t)bkv * 64 + r) * 2048 + cs;
    pv[i][1] = vlg + ((size_t)bkv * 64 + r) * 2048 + cs;
    ldsb[i] = i * 2048 + w * 512;
  }
  f32x4 o[4] = {};
  float mo[4] = {-1e30f, -1e30f, -1e30f, -1e30f};
  float lo[4] = {0.f, 0.f, 0.f, 0.f};
  for (int ks = 0; ks <= q0; ks += 64) {
    __syncthreads();
    #pragma unroll
    for (int i = 0; i < 2; i++) {
      gload16(pk[i][0] + (size_t)ks * 64, &KhS[ldsb[i]]);
      gload16(pk[i][1] + (size_t)ks * 64, &KlS[ldsb[i]]);
      gload16(pv[i][0] + ks, &VhS[ldsb[i]]);
      gload16(pv[i][1] + ks, &VlS[ldsb[i]]);
    }
    __syncthreads();
    f32x4 s[4] = {};
    __builtin_amdgcn_s_setprio(1);
    #pragma unroll
    for (int n = 0; n < 4; n++)
      #pragma unroll
      for (int kk = 0; kk < 2; kk++) {
        int ro = (n * 16 + rr) * 64 + ((kk * 32 + ko) ^ xo8);
        f16x8 kbh = *(const f16x8*)&KhS[ro];
        f16x8 kbl = *(const f16x8*)&KlS[ro];
        s[n] = mfma16(qh[kk], kbh, s[n]);
        s[n] = mfma16(qh[kk], kbl, s[n]);
        s[n] = mfma16(ql[kk], kbh, s[n]);
      }
    __builtin_amdgcn_s_setprio(0);
    bool diag = (ks == q0);
    int myrow = q0 + w * 16 + (lane >> 4) * 4;
    #pragma unroll
    for (int n = 0; n < 4; n++)
      #pragma unroll
      for (int j = 0; j < 4; j++) {
        float v = s[n][j] * 0.125f;
        if (diag && (ks + n * 16 + rr) > (myrow + j)) v = -1e30f;
        s[n][j] = v;
      }
    float mt[4];
    #pragma unroll
    for (int j = 0; j < 4; j++) mt[j] = fmaxf(fmaxf(s[0][j], s[1][j]), fmaxf(s[2][j], s[3][j]));
    #pragma unroll
    for (int msk = 1; msk < 16; msk <<= 1)
      #pragma unroll
      for (int j = 0; j < 4; j++) mt[j] = fmaxf(mt[j], __shfl_xor(mt[j], msk, 64));
    float pvv[4][4], rsum[4];
    #pragma unroll
    for (int j = 0; j < 4; j++) {
      float mn = fmaxf(mo[j], mt[j]);
      float al = expf(mo[j] - mn);
      mo[j] = mn;
      rsum[j] = 0.f;
      #pragma unroll
      for (int n = 0; n < 4; n++) { float pp = expf(s[n][j] - mn); pvv[n][j] = pp; rsum[j] += pp; }
      lo[j] *= al;
      #pragma unroll
      for (int n = 0; n < 4; n++) o[n][j] *= al;
    }
    #pragma unroll
    for (int msk = 1; msk < 16; msk <<= 1)
      #pragma unroll
      for (int j = 0; j < 4; j++) rsum[j] += __shfl_xor(rsum[j], msk, 64);
    #pragma unroll
    for (int j = 0; j < 4; j++) lo[j] += rsum[j];
    int prow = w * 16 + (lane >> 4) * 4;
    #pragma unroll
    for (int n = 0; n < 4; n++)
      #pragma unroll
      for (int j = 0; j < 4; j++) {
        _Float16 hh, ll; split16(pvv[n][j], hh, ll);
        Ph[prow + j][n * 16 + rr] = hh;
        Pl[prow + j][n * 16 + rr] = ll;
      }
    __builtin_amdgcn_s_setprio(1);
    #pragma unroll
    for (int kk = 0; kk < 2; kk++) {
      f16x8 pah = *(const f16x8*)&Ph[w * 16 + rr][kk * 32 + ko];
      f16x8 pal = *(const f16x8*)&Pl[w * 16 + rr][kk * 32 + ko];
      #pragma unroll
      for (int dn = 0; dn < 4; dn++) {
        int ro = (dn * 16 + rr) * 64 + ((kk * 32 + ko) ^ xo8);
        f16x8 vbh = *(const f16x8*)&VhS[ro];
        f16x8 vbl = *(const f16x8*)&VlS[ro];
        o[dn] = mfma16(pah, vbh, o[dn]);
        o[dn] = mfma16(pah, vbl, o[dn]);
        o[dn] = mfma16(pal, vbh, o[dn]);
      }
    }
    __builtin_amdgcn_s_setprio(0);
  }
  float inv[4];
  #pragma unroll
  for (int j = 0; j < 4; j++) inv[j] = 1.0f / lo[j];
  int orow = q0 + w * 16 + (lane >> 4) * 4;
  int ocol = h * 64 + rr;
  #pragma unroll
  for (int dn = 0; dn < 4; dn++)
    #pragma unroll
    for (int j = 0; j < 4; j++) {
      float v = o[dn][j] * inv[j];
      _Float16 hh, ll; split16(v, hh, ll);
      size_t idx = (size_t)((orow + j) * 2 + b) * HH + ocol + dn * 16;
      aoh[idx] = hh; aol[idx] = ll;
    }
}

// ---------------- Router: f32 logits, softmax, top-2, scatter to per-expert lists ----------------
__global__ __launch_bounds__(256) void router_kernel(const float* __restrict__ x,
    const float* __restrict__ rw, int* __restrict__ list, float* __restrict__ listp,
    int* __restrict__ cnt)
{
  __shared__ float rws[HH * 8];
  int tid = threadIdx.x;
  for (int i = tid; i < HH * 8; i += 256) rws[i] = rw[i];
  __syncthreads();
  int t = blockIdx.x * 4 + (tid >> 6);
  int lane = tid & 63;
  const float* xp = x + (size_t)t * HH;
  float acc[8] = {};
  for (int i = lane; i < HH; i += 64) {
    float xv = xp[i];
    #pragma unroll
    for (int e = 0; e < 8; e++) acc[e] += xv * rws[i * 8 + e];
  }
  #pragma unroll
  for (int e = 0; e < 8; e++)
    #pragma unroll
    for (int m = 1; m < 64; m <<= 1) acc[e] += __shfl_xor(acc[e], m, 64);
  if (lane == 0) {
    float mx = acc[0];
    #pragma unroll
    for (int e = 1; e < 8; e++) mx = fmaxf(mx, acc[e]);
    float p[8], sum = 0.f;
    #pragma unroll
    for (int e = 0; e < 8; e++) { p[e] = expf(acc[e] - mx); sum += p[e]; }
    float inv = 1.0f / sum;
    int i1 = 0; float v1 = acc[0];
    #pragma unroll
    for (int e = 1; e < 8; e++) if (acc[e] > v1) { v1 = acc[e]; i1 = e; }
    int i2 = -1; float v2 = -3.4e38f;
    #pragma unroll
    for (int e = 0; e < 8; e++) if (e != i1 && acc[e] > v2) { v2 = acc[e]; i2 = e; }
    int pos1 = atomicAdd(&cnt[i1], 1);
    list[i1 * TT + pos1] = t; listp[i1 * TT + pos1] = p[i1] * inv;
    int pos2 = atomicAdd(&cnt[i2], 1);
    list[i2 * TT + pos2] = t; listp[i2 * TT + pos2] = p[i2] * inv;
  }
}

// ======== MoE GEMMs: 128x128 tile, BK=32, 3-stage LDS pipeline (48KB), depth-2 prefetch ========
// Round-8 configuration (best measured). sched_barrier(0) pins removed (m141: order-pinning
// defeats compiler scheduling; asm "memory" clobber already fences the LDS reads).

// moe1: hidden = gelu(gather(xbf) @ w1T[e]^T). 1D grid, e=id&7 (XCD-pinned).
__global__ __launch_bounds__(256) void moe1_p3(const short* __restrict__ xbf,
    const short* __restrict__ w1T, const int* __restrict__ list,
    const int* __restrict__ cnt, short* __restrict__ hidden)
{
  __shared__ short A3[3][4096], B3[3][4096];   // [128][32] each, 48 KB total
  int id = blockIdx.x;
  int e = id & 7;
  int inner = id >> 3;
  int mx = inner & 31, nx = inner >> 5;
  int ce = cnt[e];
  int m0 = mx * 128;
  if (m0 >= ce) return;                        // block-uniform, before any barrier
  int n0 = nx * 128;
  int off = 0;
  #pragma unroll
  for (int i = 0; i < 8; i++) if (i < e) off += cnt[i];
  const int tid = threadIdx.x, lane = tid & 63, w = tid >> 6;
  const int wr = w >> 1, wc = w & 1;
  f32x4 acc[4][4] = {};
  const short *pa[2], *pb[2];
  int lof[2];
  #pragma unroll
  for (int i = 0; i < 2; i++) {
    int E = i * 2048 + w * 512 + lane * 8;
    int r = E >> 5, c = E & 31;
    int cs = c ^ ((r & 3) << 3);
    int apos = m0 + r; if (apos > ce - 1) apos = ce - 1;
    int tok = list[e * TT + apos];
    pa[i] = xbf + (size_t)tok * HH + cs;
    pb[i] = w1T + ((size_t)e * FF + n0 + r) * HH + cs;
    lof[i] = E;
  }
  const int rr = lane & 15, ko = (lane >> 4) * 8;
  const int koX = ko ^ ((rr & 3) << 3);
  const int T = HH / 32;                       // 32
  // prologue: stage tiles 0,1 into bufs 0,1
  #pragma unroll
  for (int i = 0; i < 2; i++) {
    gload16(pa[i], &A3[0][lof[i]]);
    gload16(pb[i], &B3[0][lof[i]]);
  }
  #pragma unroll
  for (int i = 0; i < 2; i++) {
    gload16(pa[i] + 32, &A3[1][lof[i]]);
    gload16(pb[i] + 32, &B3[1][lof[i]]);
  }
  int cb = 0;
  for (int t = 0; t < T; t++) {
    if (t + 2 < T) {
      int k0 = (t + 2) * 32;
      int nb = cb + 2; if (nb >= 3) nb -= 3;
      #pragma unroll
      for (int i = 0; i < 2; i++) {
        gload16(pa[i] + k0, &A3[nb][lof[i]]);
        gload16(pb[i] + k0, &B3[nb][lof[i]]);
      }
      asm volatile("s_waitcnt vmcnt(8)" ::: "memory");
    } else if (t + 1 < T) {
      asm volatile("s_waitcnt vmcnt(4)" ::: "memory");
    } else {
      asm volatile("s_waitcnt vmcnt(0)" ::: "memory");
    }
    __builtin_amdgcn_s_barrier();
    bf16x8 fa[4], fb[4];
    #pragma unroll
    for (int m = 0; m < 4; m++) fa[m] = *(const bf16x8*)&A3[cb][(wr * 64 + m * 16 + rr) * 32 + koX];
    #pragma unroll
    for (int n = 0; n < 4; n++) fb[n] = *(const bf16x8*)&B3[cb][(wc * 64 + n * 16 + rr) * 32 + koX];
    __builtin_amdgcn_s_setprio(1);
    #pragma unroll
    for (int m = 0; m < 4; m++)
      #pragma unroll
      for (int n = 0; n < 4; n++) acc[m][n] = mfmabf(fa[m], fb[n], acc[m][n]);
    __builtin_amdgcn_s_setprio(0);
    asm volatile("s_waitcnt lgkmcnt(0)" ::: "memory");
    __builtin_amdgcn_s_barrier();
    cb += 1; if (cb >= 3) cb -= 3;
  }
  int p0 = m0 + wr * 64 + (lane >> 4) * 4;
  int c0 = n0 + wc * 64 + (lane & 15);
  #pragma unroll
  for (int m = 0; m < 4; m++)
    #pragma unroll
    for (int n = 0; n < 4; n++)
      #pragma unroll
      for (int j = 0; j < 4; j++) {
        int pos = p0 + m * 16 + j;
        if (pos < ce) {
          float v = fast_gelu(acc[m][n][j]);
          hidden[(size_t)(off + pos) * FF + c0 + n * 16] = f2bf(v);
        }
      }
}

// moe2: out[tok] += p * (hidden @ w2T[e]^T), split-K x2, atomic epilogue.
// id: e=id&7; r=id>>3: mx=r&31, nx=(r>>5)&7, ksp=r>>8.
__global__ __launch_bounds__(256) void moe2_p3(const short* __restrict__ hidden,
    const short* __restrict__ w2T, const int* __restrict__ list,
    const float* __restrict__ listp, const int* __restrict__ cnt,
    float* __restrict__ outp)
{
  __shared__ short A3[3][4096], B3[3][4096];
  int id = blockIdx.x;
  int e = id & 7;
  int r_ = id >> 3;
  int mx = r_ & 31, nx = (r_ >> 5) & 7, ksp = r_ >> 8;
  int ce = cnt[e];
  int m0 = mx * 128;
  if (m0 >= ce) return;
  int n0 = nx * 128;
  int kbase = ksp * (FF / 2);
  int off = 0;
  #pragma unroll
  for (int i = 0; i < 8; i++) if (i < e) off += cnt[i];
  const int tid = threadIdx.x, lane = tid & 63, w = tid >> 6;
  const int wr = w >> 1, wc = w & 1;
  f32x4 acc[4][4] = {};
  const short *pa[2], *pb[2];
  int lof[2];
  #pragma unroll
  for (int i = 0; i < 2; i++) {
    int E = i * 2048 + w * 512 + lane * 8;
    int r = E >> 5, c = E & 31;
    int cs = c ^ ((r & 3) << 3);
    int apos = m0 + r; if (apos > ce - 1) apos = ce - 1;
    pa[i] = hidden + ((size_t)off + apos) * FF + kbase + cs;
    pb[i] = w2T + ((size_t)e * HH + n0 + r) * FF + kbase + cs;
    lof[i] = E;
  }
  const int rr = lane & 15, ko = (lane >> 4) * 8;
  const int koX = ko ^ ((rr & 3) << 3);
  const int T = (FF / 2) / 32;                 // 64
  #pragma unroll
  for (int i = 0; i < 2; i++) {
    gload16(pa[i], &A3[0][lof[i]]);
    gload16(pb[i], &B3[0][lof[i]]);
  }
  #pragma unroll
  for (int i = 0; i < 2; i++) {
    gload16(pa[i] + 32, &A3[1][lof[i]]);
    gload16(pb[i] + 32, &B3[1][lof[i]]);
  }
  int cb = 0;
  for (int t = 0; t < T; t++) {
    if (t + 2 < T) {
      int k0 = (t + 2) * 32;
      int nb = cb + 2; if (nb >= 3) nb -= 3;
      #pragma unroll
      for (int i = 0; i < 2; i++) {
        gload16(pa[i] + k0, &A3[nb][lof[i]]);
        gload16(pb[i] + k0, &B3[nb][lof[i]]);
      }
      asm volatile("s_waitcnt vmcnt(8)" ::: "memory");
    } else if (t + 1 < T) {
      asm volatile("s_waitcnt vmcnt(4)" ::: "memory");
    } else {
      asm volatile("s_waitcnt vmcnt(0)" ::: "memory");
    }
    __builtin_amdgcn_s_barrier();
    bf16x8 fa[4], fb[4];
    #pragma unroll
    for (int m = 0; m < 4; m++) fa[m] = *(const bf16x8*)&A3[cb][(wr * 64 + m * 16 + rr) * 32 + koX];
    #pragma unroll
    for (int n = 0; n < 4; n++) fb[n] = *(const bf16x8*)&B3[cb][(wc * 64 + n * 16 + rr) * 32 + koX];
    __builtin_amdgcn_s_setprio(1);
    #pragma unroll
    for (int m = 0; m < 4; m++)
      #pragma unroll
      for (int n = 0; n < 4; n++) acc[m][n] = mfmabf(fa[m], fb[n], acc[m][n]);
    __builtin_amdgcn_s_setprio(0);
    asm volatile("s_waitcnt lgkmcnt(0)" ::: "memory");
    __builtin_amdgcn_s_barrier();
    cb += 1; if (cb >= 3) cb -= 3;
  }
  int p0 = m0 + wr * 64 + (lane >> 4) * 4;
  int c0 = n0 + wc * 64 + (lane & 15);
  #pragma unroll
  for (int m = 0; m < 4; m++)
    #pragma unroll
    for (int j = 0; j < 4; j++) {
      int pos = p0 + m * 16 + j;
      if (pos < ce) {
        int tk = list[e * TT + pos];
        float pw = listp[e * TT + pos];
        #pragma unroll
        for (int n = 0; n < 4; n++)
          atomicAdd(&outp[(size_t)tk * HH + c0 + n * 16], pw * acc[m][n][j]);
      }
    }
}

// ---------------- fallback MoE kernels (round-1, known-good; used when ws is small) -----------
__global__ __launch_bounds__(256) void moe_gemm1(const float* __restrict__ x,
    const float* __restrict__ w1, const int* __restrict__ list,
    const int* __restrict__ cnt, short* __restrict__ hidden, int e)
{
  int ce = cnt[e];
  int m0 = blockIdx.y * 128;
  if (m0 >= ce) return;
  int n0 = blockIdx.x * 128;
  __shared__ short As[128][40], Bs[128][40];
  int tid = threadIdx.x, lane = tid & 63, w = tid >> 6, wr = w >> 1, wc = w & 1;
  f32x4 acc[4][4] = {};
  int arow = tid >> 1, akh = (tid & 1) * 16;
  int apos = m0 + arow;
  int tok = list[(size_t)e * TT + (apos < ce ? apos : 0)];
  const float* ap = x + (size_t)tok * HH + akh;
  int bn = tid & 127, bkh = (tid >> 7) * 16;
  const float* bp = w1 + (size_t)e * HH * FF + (size_t)bkh * FF + n0 + bn;
  for (int k0 = 0; k0 < HH; k0 += 32) {
    __syncthreads();
    {
      const float4* p = (const float4*)(ap + k0);
      bf16x8 s0, s1;
      #pragma unroll
      for (int q = 0; q < 2; q++) { float4 v = p[q]; s0[q*4] = f2bf(v.x); s0[q*4+1] = f2bf(v.y); s0[q*4+2] = f2bf(v.z); s0[q*4+3] = f2bf(v.w); }
      #pragma unroll
      for (int q = 0; q < 2; q++) { float4 v = p[q+2]; s1[q*4] = f2bf(v.x); s1[q*4+1] = f2bf(v.y); s1[q*4+2] = f2bf(v.z); s1[q*4+3] = f2bf(v.w); }
      *(bf16x8*)&As[arow][akh] = s0; *(bf16x8*)&As[arow][akh+8] = s1;
    }
    {
      const float* p = bp + (size_t)k0 * FF;
      bf16x8 s0, s1;
      #pragma unroll
      for (int q = 0; q < 8; q++) s0[q] = f2bf(p[(size_t)q * FF]);
      #pragma unroll
      for (int q = 0; q < 8; q++) s1[q] = f2bf(p[(size_t)(q+8) * FF]);
      *(bf16x8*)&Bs[bn][bkh] = s0; *(bf16x8*)&Bs[bn][bkh+8] = s1;
    }
    __syncthreads();
    int rr = lane & 15, ko = (lane >> 4) * 8;
    bf16x8 fa[4], fb[4];
    #pragma unroll
    for (int m = 0; m < 4; m++) fa[m] = *(bf16x8*)&As[wr*64 + m*16 + rr][ko];
    #pragma unroll
    for (int n = 0; n < 4; n++) fb[n] = *(bf16x8*)&Bs[wc*64 + n*16 + rr][ko];
    #pragma unroll
    for (int m = 0; m < 4; m++)
      #pragma unroll
      for (int n = 0; n < 4; n++) acc[m][n] = mfmabf(fa[m], fb[n], acc[m][n]);
  }
  int p0 = m0 + wr*64 + (lane >> 4) * 4;
  int c0 = n0 + wc*64 + (lane & 15);
  #pragma unroll
  for (int m = 0; m < 4; m++)
    #pragma unroll
    for (int n = 0; n < 4; n++)
      #pragma unroll
      for (int j = 0; j < 4; j++) {
        int pos = p0 + m*16 + j;
        if (pos < ce) {
          float v = acc[m][n][j];
          v = 0.5f * v * (1.0f + erff(v * 0.70710678f));
          hidden[(size_t)pos * FF + c0 + n*16] = f2bf(v);
        }
      }
}

__global__ __launch_bounds__(256) void moe_gemm2(const short* __restrict__ hidden,
    const float* __restrict__ w2, const int* __restrict__ list,
    const float* __restrict__ listp, const int* __restrict__ cnt,
    float* __restrict__ outp, int e)
{
  int ce = cnt[e];
  int m0 = blockIdx.y * 128;
  if (m0 >= ce) return;
  int n0 = blockIdx.x * 128;
  __shared__ short As[128][40], Bs[128][40];
  int tid = threadIdx.x, lane = tid & 63, w = tid >> 6, wr = w >> 1, wc = w & 1;
  f32x4 acc[4][4] = {};
  int arow = tid >> 1, akh = (tid & 1) * 16;
  int apos = m0 + arow;
  const short* ap = hidden + (size_t)(apos < ce ? apos : 0) * FF + akh;
  int bn = tid & 127, bkh = (tid >> 7) * 16;
  const float* bp = w2 + (size_t)e * FF * HH + (size_t)bkh * HH + n0 + bn;
  for (int k0 = 0; k0 < FF; k0 += 32) {
    __syncthreads();
    {
      const int4* p = (const int4*)(ap + k0);
      int4 a0 = p[0], a1 = p[1];
      *(int4*)&As[arow][akh]   = a0;
      *(int4*)&As[arow][akh+8] = a1;
    }
    {
      const float* p = bp + (size_t)k0 * HH;
      bf16x8 s0, s1;
      #pragma unroll
      for (int q = 0; q < 8; q++) s0[q] = f2bf(p[(size_t)q * HH]);
      #pragma unroll
      for (int q = 0; q < 8; q++) s1[q] = f2bf(p[(size_t)(q+8) * HH]);
      *(bf16x8*)&Bs[bn][bkh] = s0; *(bf16x8*)&Bs[bn][bkh+8] = s1;
    }
    __syncthreads();
    int rr = lane & 15, ko = (lane >> 4) * 8;
    bf16x8 fa[4], fb[4];
    #pragma unroll
    for (int m = 0; m < 4; m++) fa[m] = *(bf16x8*)&As[wr*64 + m*16 + rr][ko];
    #pragma unroll
    for (int n = 0; n < 4; n++) fb[n] = *(bf16x8*)&Bs[wc*64 + n*16 + rr][ko];
    #pragma unroll
    for (int m = 0; m < 4; m++)
      #pragma unroll
      for (int n = 0; n < 4; n++) acc[m][n] = mfmabf(fa[m], fb[n], acc[m][n]);
  }
  int p0 = m0 + wr*64 + (lane >> 4) * 4;
  int c0 = n0 + wc*64 + (lane & 15);
  #pragma unroll
  for (int m = 0; m < 4; m++)
    #pragma unroll
    for (int j = 0; j < 4; j++) {
      int pos = p0 + m*16 + j;
      if (pos < ce) {
        int tk = list[(size_t)e * TT + pos];
        float pw = listp[(size_t)e * TT + pos];
        #pragma unroll
        for (int n = 0; n < 4; n++)
          atomicAdd(&outp[(size_t)tk * HH + c0 + n*16], pw * acc[m][n][j]);
      }
    }
}

extern "C" void kernel_launch(void* const* d_in, const int* in_sizes, int n_in,
                              void* d_out, int out_size, void* d_ws, size_t ws_size,
                              hipStream_t stream)
{
  const float* hs      = (const float*)d_in[0];
  const float* ln1w    = (const float*)d_in[1];
  const float* ln1b    = (const float*)d_in[2];
  const float* ln2w    = (const float*)d_in[3];
  const float* ln2b    = (const float*)d_in[4];
  const float* qkvw    = (const float*)d_in[5];
  const float* projw   = (const float*)d_in[6];
  const float* routerw = (const float*)d_in[7];
  const float* w1      = (const float*)d_in[8];
  const float* w2      = (const float*)d_in[9];
  float* out = (float*)d_out;

  const size_t MB = 1024 * 1024;
  char* wsb = (char*)d_ws;
  bool full = ws_size >= 153 * MB;

  float*    qkvbuf = (float*)wsb;
  _Float16* khb    = (_Float16*)(wsb + 24 * MB);
  _Float16* klb    = (_Float16*)(wsb + 26 * MB);
  _Float16* vhb    = (_Float16*)(wsb + 28 * MB);
  _Float16* vlb    = (_Float16*)(wsb + 30 * MB);
  short*    hidden = (short*)wsb;
  size_t r2 = full ? 64 * MB : 32 * MB;
  _Float16* ln1h = (_Float16*)(wsb + r2);
  _Float16* ln1l = (_Float16*)(wsb + r2 + 8 * MB);
  _Float16* aohb = ln1h;
  _Float16* aolb = ln1l;
  float*    xbuf = (float*)(wsb + r2);
  short*    xbf  = (short*)(wsb + r2 + 16 * MB);
  size_t r3 = full ? 88 * MB : 56 * MB;
  _Float16* qkvwTh  = (_Float16*)(wsb + r3);
  _Float16* qkvwTl  = (_Float16*)(wsb + r3 + 3 * MB);
  _Float16* projwTh = (_Float16*)(wsb + r3 + 6 * MB);
  _Float16* projwTl = (_Float16*)(wsb + r3 + 8 * MB);
  short*    w1T     = (short*)(wsb + r3);
  short*    w2T     = (short*)(wsb + r3);
  size_t r4 = full ? 152 * MB : 66 * MB;
  int*   list  = (int*)(wsb + r4);
  float* listp = (float*)(wsb + r4 + 128 * 1024);
  int*   cnt   = (int*)(wsb + r4 + 256 * 1024);

  zero_cnt<<<1, 64, 0, stream>>>(cnt);
  wconv_split<<<dim3(QKVN / 64, HH / 64), 256, 0, stream>>>(qkvw, qkvwTh, qkvwTl, HH, QKVN);
  wconv_split<<<dim3(HH / 64, HH / 64), 256, 0, stream>>>(projw, projwTh, projwTl, HH, HH);
  ln_split<0><<<TT, 256, 0, stream>>>(hs, ln1w, ln1b, ln1h, ln1l, nullptr, nullptr);
  gemm_split2<0><<<dim3(QKVN / 128, TT / 128), 256, 0, stream>>>(
      ln1h, ln1l, qkvwTh, qkvwTl, HH, qkvbuf, QKVN, nullptr, khb, klb);
  vtrans<<<dim3(8, 32), 256, 0, stream>>>(qkvbuf, vhb, vlb);
  attn2<<<dim3(32, 32), 256, 0, stream>>>(qkvbuf, khb, klb, vhb, vlb, aohb, aolb);
  gemm_split2<1><<<dim3(HH / 128, TT / 128), 256, 0, stream>>>(
      aohb, aolb, projwTh, projwTl, HH, out, HH, hs, nullptr, nullptr);
  ln_split<1><<<TT, 256, 0, stream>>>(out, ln2w, ln2b, nullptr, nullptr, xbuf, xbf);
  router_kernel<<<TT / 4, 256, 0, stream>>>(xbuf, routerw, list, listp, cnt);
  if (full) {
    wconv_bf<<<dim3(FF / 64, HH / 64, 8), 256, 0, stream>>>(w1, w1T, HH, FF);
    moe1_p3<<<8 * 32 * 32, 256, 0, stream>>>(xbf, w1T, list, cnt, hidden);
    wconv_bf<<<dim3(HH / 64, FF / 64, 8), 256, 0, stream>>>(w2, w2T, FF, HH);
    moe2_p3<<<8 * 32 * 8 * 2, 256, 0, stream>>>(hidden, w2T, list, listp, cnt, out);
  } else {
    for (int e = 0; e < 8; e++) {
      moe_gemm1<<<dim3(FF / 128, TT / 128), 256, 0, stream>>>(xbuf, w1, list, cnt, hidden, e);
      moe_gemm2<<<dim3(HH / 128, TT / 128), 256, 0, stream>>>(hidden, w2, list, listp, cnt, out, e);
    }
  }
}

// Round 13
// 660.561 us; speedup vs baseline: 1.1979x; 1.0357x over previous
//
#include <hip/hip_runtime.h>
#include <hip/hip_bf16.h>

// Problem constants (S=2048, B=2, H=1024, NH=16, NKV=4, HD=64, E=8, K=2, F=4096)
constexpr int TT   = 4096;   // S*B tokens
constexpr int HH   = 1024;
constexpr int QKVN = 1536;
constexpr int FF   = 4096;

using f16x8  = __attribute__((ext_vector_type(8))) _Float16;
using f16x4  = __attribute__((ext_vector_type(4))) _Float16;
using bf16x8 = __attribute__((ext_vector_type(8))) short;
using s16x4  = __attribute__((ext_vector_type(4))) short;
using f32x4  = __attribute__((ext_vector_type(4))) float;

static __device__ __forceinline__ f32x4 mfma16(f16x8 a, f16x8 b, f32x4 c) {
  return __builtin_amdgcn_mfma_f32_16x16x32_f16(a, b, c, 0, 0, 0);
}
static __device__ __forceinline__ f32x4 mfmabf(bf16x8 a, bf16x8 b, f32x4 c) {
  return __builtin_amdgcn_mfma_f32_16x16x32_bf16(a, b, c, 0, 0, 0);
}
static __device__ __forceinline__ short f2bf(float f) {
  union { float f; unsigned u; } v; v.f = f;
  unsigned r = v.u + 0x7fffu + ((v.u >> 16) & 1u);
  return (short)(r >> 16);
}
static __device__ __forceinline__ void split16(float f, _Float16 &h, _Float16 &l) {
  _Float16 hh = (_Float16)f; h = hh; l = (_Float16)(f - (float)hh);
}
// fast tanh-gelu (max |diff| vs exact-gelu ~3e-3; hidden is bf16 anyway)
static __device__ __forceinline__ float fast_gelu(float x) {
  float u = 0.7978845608f * (x + 0.044715f * x * x * x);
  float a = __expf(-2.0f * fabsf(u));
  float t = (1.0f - a) * __builtin_amdgcn_rcpf(1.0f + a);
  t = copysignf(t, u);
  return 0.5f * x * (1.0f + t);
}
// async global->LDS, 16B per lane. LDS ptr must be wave-uniform; global ptr is per-lane.
static __device__ __forceinline__ void gload16(const void* g, void* l) {
  __builtin_amdgcn_global_load_lds((__attribute__((address_space(1))) void*)(g),
                                   (__attribute__((address_space(3))) void*)(l), 16, 0, 0);
}

__global__ void zero_cnt(int* cnt) { if (threadIdx.x < 8) cnt[threadIdx.x] = 0; }

// ---------------- weight transpose + fp16 hi/lo split: W[K][N] f32 -> out[N][K] f16 x2 ----------
__global__ __launch_bounds__(256) void wconv_split(const float* __restrict__ W,
    _Float16* __restrict__ oh, _Float16* __restrict__ ol, int K, int N)
{
  __shared__ float ts[64][68];
  int n0 = blockIdx.x * 64, k0 = blockIdx.y * 64, t = threadIdx.x;
  #pragma unroll
  for (int it = 0; it < 4; it++) {
    int el = it * 1024 + t * 4; int r = el >> 6, c = el & 63;
    float4 v = *(const float4*)&W[(size_t)(k0 + r) * N + n0 + c];
    *(float4*)&ts[r][c] = v;
  }
  __syncthreads();
  #pragma unroll
  for (int it = 0; it < 4; it++) {
    int el = it * 1024 + t * 4; int nr = el >> 6, kc = el & 63;
    f16x4 hv, lv;
    #pragma unroll
    for (int q = 0; q < 4; q++) { _Float16 hh, ll; split16(ts[kc + q][nr], hh, ll); hv[q] = hh; lv[q] = ll; }
    size_t o = (size_t)(n0 + nr) * K + k0 + kc;
    *(f16x4*)&oh[o] = hv; *(f16x4*)&ol[o] = lv;
  }
}

// ---------------- weight transpose to bf16 (batched over experts via z): W[z][K][N] -> out[z][N][K]
__global__ __launch_bounds__(256) void wconv_bf(const float* __restrict__ W,
    short* __restrict__ o, int K, int N)
{
  __shared__ float ts[64][68];
  const float* Wz = W + (size_t)blockIdx.z * K * N;
  short* oz = o + (size_t)blockIdx.z * K * N;
  int n0 = blockIdx.x * 64, k0 = blockIdx.y * 64, t = threadIdx.x;
  #pragma unroll
  for (int it = 0; it < 4; it++) {
    int el = it * 1024 + t * 4; int r = el >> 6, c = el & 63;
    float4 v = *(const float4*)&Wz[(size_t)(k0 + r) * N + n0 + c];
    *(float4*)&ts[r][c] = v;
  }
  __syncthreads();
  #pragma unroll
  for (int it = 0; it < 4; it++) {
    int el = it * 1024 + t * 4; int nr = el >> 6, kc = el & 63;
    s16x4 bv;
    #pragma unroll
    for (int q = 0; q < 4; q++) bv[q] = f2bf(ts[kc + q][nr]);
    *(s16x4*)&oz[(size_t)(n0 + nr) * K + k0 + kc] = bv;
  }
}

// ---------------- V transpose: qkv f32 V-cols -> vt[bkv][d][s] f16 hi/lo ----------------
__global__ __launch_bounds__(256) void vtrans(const float* __restrict__ qkv,
    _Float16* __restrict__ vh, _Float16* __restrict__ vl)
{
  __shared__ float ts[64][68];
  int bkv = blockIdx.x, b = bkv >> 2, kvh = bkv & 3;
  int s0 = blockIdx.y * 64, t = threadIdx.x;
  #pragma unroll
  for (int it = 0; it < 4; it++) {
    int el = it * 1024 + t * 4; int r = el >> 6, c = el & 63;
    float4 v = *(const float4*)&qkv[(size_t)((s0 + r) * 2 + b) * QKVN + 1280 + kvh * 64 + c];
    *(float4*)&ts[r][c] = v;
  }
  __syncthreads();
  #pragma unroll
  for (int it = 0; it < 4; it++) {
    int el = it * 1024 + t * 4; int d = el >> 6, sc = el & 63;
    f16x4 hv, lv;
    #pragma unroll
    for (int q = 0; q < 4; q++) { _Float16 hh, ll; split16(ts[sc + q][d], hh, ll); hv[q] = hh; lv[q] = ll; }
    size_t o = ((size_t)bkv * 64 + d) * 2048 + s0 + sc;
    *(f16x4*)&vh[o] = hv; *(f16x4*)&vl[o] = lv;
  }
}

// ---------------- LayerNorm, f32 math. MODE 0: emit fp16 hi/lo. MODE 1: emit f32 + bf16 -------
template<int MODE>
__global__ __launch_bounds__(256) void ln_split(const float* __restrict__ in,
    const float* __restrict__ wt, const float* __restrict__ bs,
    _Float16* __restrict__ oh, _Float16* __restrict__ ol,
    float* __restrict__ xo, short* __restrict__ xbo)
{
  int row = blockIdx.x, tid = threadIdx.x;
  const float4* ip = (const float4*)(in + (size_t)row * HH);
  float4 v = ip[tid];
  float s = v.x + v.y + v.z + v.w;
  #pragma unroll
  for (int m = 1; m < 64; m <<= 1) s += __shfl_xor(s, m, 64);
  __shared__ float red1[4], red2[4];
  int wid = tid >> 6;
  if ((tid & 63) == 0) red1[wid] = s;
  __syncthreads();
  float mu = (red1[0] + red1[1] + red1[2] + red1[3]) * (1.0f / HH);
  float4 c; c.x = v.x - mu; c.y = v.y - mu; c.z = v.z - mu; c.w = v.w - mu;
  float s2 = c.x*c.x + c.y*c.y + c.z*c.z + c.w*c.w;
  #pragma unroll
  for (int m = 1; m < 64; m <<= 1) s2 += __shfl_xor(s2, m, 64);
  if ((tid & 63) == 0) red2[wid] = s2;
  __syncthreads();
  float ve = (red2[0] + red2[1] + red2[2] + red2[3]) * (1.0f / HH) + 1e-5f;
  float rs = rsqrtf(ve);
  rs = rs * (1.5f - 0.5f * ve * rs * rs);
  float4 wv = ((const float4*)wt)[tid], bv = ((const float4*)bs)[tid];
  float o4[4];
  o4[0] = c.x * rs * wv.x + bv.x; o4[1] = c.y * rs * wv.y + bv.y;
  o4[2] = c.z * rs * wv.z + bv.z; o4[3] = c.w * rs * wv.w + bv.w;
  size_t base = (size_t)row * HH + tid * 4;
  if (MODE == 0) {
    f16x4 hv, lv;
    #pragma unroll
    for (int q = 0; q < 4; q++) { _Float16 hh, ll; split16(o4[q], hh, ll); hv[q] = hh; lv[q] = ll; }
    *(f16x4*)&oh[base] = hv; *(f16x4*)&ol[base] = lv;
  } else {
    float4 ov; ov.x = o4[0]; ov.y = o4[1]; ov.z = o4[2]; ov.w = o4[3];
    *(float4*)&xo[base] = ov;
    s16x4 bvv;
    #pragma unroll
    for (int q = 0; q < 4; q++) bvv[q] = f2bf(o4[q]);
    *(s16x4*)&xbo[base] = bvv;
  }
}

// ------- fp16-split GEMM, m97-style: global_load_lds staging, 128x128 tile, BK=32, 3-pass MFMA
template<int EPI>
__global__ __launch_bounds__(256) void gemm_split2(
    const _Float16* __restrict__ Agh, const _Float16* __restrict__ Agl,
    const _Float16* __restrict__ Bgh, const _Float16* __restrict__ Bgl,
    int K, float* __restrict__ C, int ldc, const float* __restrict__ resid,
    _Float16* __restrict__ kh, _Float16* __restrict__ kl)
{
  __shared__ _Float16 AhS[4096], AlS[4096], BhS[4096], BlS[4096];
  const int tid = threadIdx.x, lane = tid & 63, w = tid >> 6;
  const int wr = w >> 1, wc = w & 1;
  const int m0 = blockIdx.y * 128, n0 = blockIdx.x * 128;
  f32x4 acc[4][4] = {};
  const _Float16 *pah[2], *pal[2], *pbh[2], *pbl[2];
  int ldsb[2];
  #pragma unroll
  for (int i = 0; i < 2; i++) {
    int E = i * 2048 + w * 512 + lane * 8;
    int r = E >> 5, cc = E & 31;
    int cs = cc ^ ((r & 3) << 3);
    pah[i] = Agh + (size_t)(m0 + r) * K + cs;
    pal[i] = Agl + (size_t)(m0 + r) * K + cs;
    pbh[i] = Bgh + (size_t)(n0 + r) * K + cs;
    pbl[i] = Bgl + (size_t)(n0 + r) * K + cs;
    ldsb[i] = i * 2048 + w * 512;
  }
  const int rr = lane & 15, ko = (lane >> 4) * 8;
  const int xo = (rr & 3) << 3;
  for (int k0 = 0; k0 < K; k0 += 32) {
    __syncthreads();
    #pragma unroll
    for (int i = 0; i < 2; i++) {
      gload16(pah[i] + k0, &AhS[ldsb[i]]);
      gload16(pal[i] + k0, &AlS[ldsb[i]]);
      gload16(pbh[i] + k0, &BhS[ldsb[i]]);
      gload16(pbl[i] + k0, &BlS[ldsb[i]]);
    }
    __syncthreads();
    f16x8 fah[4], fal[4], fbh[4], fbl[4];
    #pragma unroll
    for (int m = 0; m < 4; m++) {
      int ro = (wr * 64 + m * 16 + rr) * 32 + (ko ^ xo);
      fah[m] = *(const f16x8*)&AhS[ro];
      fal[m] = *(const f16x8*)&AlS[ro];
    }
    #pragma unroll
    for (int n = 0; n < 4; n++) {
      int ro = (wc * 64 + n * 16 + rr) * 32 + (ko ^ xo);
      fbh[n] = *(const f16x8*)&BhS[ro];
      fbl[n] = *(const f16x8*)&BlS[ro];
    }
    #pragma unroll
    for (int m = 0; m < 4; m++)
      #pragma unroll
      for (int n = 0; n < 4; n++) {
        acc[m][n] = mfma16(fah[m], fbh[n], acc[m][n]);
        acc[m][n] = mfma16(fah[m], fbl[n], acc[m][n]);
        acc[m][n] = mfma16(fal[m], fbh[n], acc[m][n]);
      }
  }
  int r0 = m0 + wr * 64 + (lane >> 4) * 4;
  int c0 = n0 + wc * 64 + (lane & 15);
  #pragma unroll
  for (int m = 0; m < 4; m++)
    #pragma unroll
    for (int n = 0; n < 4; n++)
      #pragma unroll
      for (int j = 0; j < 4; j++) {
        int tr = r0 + m * 16 + j, tc = c0 + n * 16;
        size_t idx = (size_t)tr * ldc + tc;
        float v = acc[m][n][j];
        if (EPI == 1) v += resid[idx];
        C[idx] = v;
        if (EPI == 0 && tc >= 1024 && tc < 1280) {
          int s = tr >> 1, bb = tr & 1;
          int kvh = (tc - 1024) >> 6, d = (tc - 1024) & 63;
          _Float16 hh, ll; split16(v, hh, ll);
          size_t kidx = ((size_t)(bb * 4 + kvh) * 2048 + s) * 64 + d;
          kh[kidx] = hh; kl[kidx] = ll;
        }
      }
}

// ---------------- Flash attention: gload staging of pre-split K / V^T, XOR-swizzled ----------
__global__ __launch_bounds__(256) void attn2(const float* __restrict__ qkv,
    const _Float16* __restrict__ khg, const _Float16* __restrict__ klg,
    const _Float16* __restrict__ vhg, const _Float16* __restrict__ vlg,
    _Float16* __restrict__ aoh, _Float16* __restrict__ aol)
{
  __shared__ _Float16 KhS[4096], KlS[4096], VhS[4096], VlS[4096];
  __shared__ _Float16 Ph[64][72], Pl[64][72];
  int bh = blockIdx.x;
  int qt = gridDim.y - 1 - blockIdx.y;    // LPT: longest (largest qt) dispatched first
  int h = bh >> 1, b = bh & 1, kvh = h >> 2, bkv = b * 4 + kvh;
  int q0 = qt * 64;
  int tid = threadIdx.x, lane = tid & 63, w = tid >> 6;
  int rr = lane & 15, ko = (lane >> 4) * 8;
  const int xo8 = (rr & 7) << 3;
  int qrow = q0 + w * 16 + rr;
  const float* qp = qkv + (size_t)(qrow * 2 + b) * QKVN + h * 64;
  f16x8 qh[2], ql[2];
  #pragma unroll
  for (int kk = 0; kk < 2; kk++) {
    const float4* p = (const float4*)(qp + kk * 32 + ko);
    float4 v0 = p[0], v1 = p[1];
    float tq[8] = {v0.x, v0.y, v0.z, v0.w, v1.x, v1.y, v1.z, v1.w};
    f16x8 hv, lv;
    #pragma unroll
    for (int q = 0; q < 8; q++) { _Float16 hh, ll; split16(tq[q], hh, ll); hv[q] = hh; lv[q] = ll; }
    qh[kk] = hv; ql[kk] = lv;
  }
  const _Float16 *pk[2][2], *pv[2][2];
  int ldsb[2];
  #pragma unroll
  for (int i = 0; i < 2; i++) {
    int E = i * 2048 + w * 512 + lane * 8;
    int r = E >> 6, cc = E & 63;
    int cs = cc ^ ((r & 7) << 3);
    pk[i][0] = khg + ((size_t)bkv * 2048 + r) * 64 + cs;
    pk[i][1] = klg + ((size_t)bkv * 2048 + r) * 64 + cs;
    pv[i][0] = vhg + ((size_t)bkv * 64 + r) * 2048 + cs;
    pv[i][1] = vlg + ((size_t)bkv * 64 + r) * 2048 + cs;
    ldsb[i] = i * 2048 + w * 512;
  }
  f32x4 o[4] = {};
  float mo[4] = {-1e30f, -1e30f, -1e30f, -1e30f};
  float lo[4] = {0.f, 0.f, 0.f, 0.f};
  for (int ks = 0; ks <= q0; ks += 64) {
    __syncthreads();
    #pragma unroll
    for (int i = 0; i < 2; i++) {
      gload16(pk[i][0] + (size_t)ks * 64, &KhS[ldsb[i]]);
      gload16(pk[i][1] + (size_t)ks * 64, &KlS[ldsb[i]]);
      gload16(pv[i][0] + ks, &VhS[ldsb[i]]);
      gload16(pv[i][1] + ks, &VlS[ldsb[i]]);
    }
    __syncthreads();
    f32x4 s[4] = {};
    __builtin_amdgcn_s_setprio(1);
    #pragma unroll
    for (int n = 0; n < 4; n++)
      #pragma unroll
      for (int kk = 0; kk < 2; kk++) {
        int ro = (n * 16 + rr) * 64 + ((kk * 32 + ko) ^ xo8);
        f16x8 kbh = *(const f16x8*)&KhS[ro];
        f16x8 kbl = *(const f16x8*)&KlS[ro];
        s[n] = mfma16(qh[kk], kbh, s[n]);
        s[n] = mfma16(qh[kk], kbl, s[n]);
        s[n] = mfma16(ql[kk], kbh, s[n]);
      }
    __builtin_amdgcn_s_setprio(0);
    bool diag = (ks == q0);
    int myrow = q0 + w * 16 + (lane >> 4) * 4;
    #pragma unroll
    for (int n = 0; n < 4; n++)
      #pragma unroll
      for (int j = 0; j < 4; j++) {
        float v = s[n][j] * 0.125f;
        if (diag && (ks + n * 16 + rr) > (myrow + j)) v = -1e30f;
        s[n][j] = v;
      }
    float mt[4];
    #pragma unroll
    for (int j = 0; j < 4; j++) mt[j] = fmaxf(fmaxf(s[0][j], s[1][j]), fmaxf(s[2][j], s[3][j]));
    #pragma unroll
    for (int msk = 1; msk < 16; msk <<= 1)
      #pragma unroll
      for (int j = 0; j < 4; j++) mt[j] = fmaxf(mt[j], __shfl_xor(mt[j], msk, 64));
    float pvv[4][4], rsum[4];
    #pragma unroll
    for (int j = 0; j < 4; j++) {
      float mn = fmaxf(mo[j], mt[j]);
      float al = expf(mo[j] - mn);
      mo[j] = mn;
      rsum[j] = 0.f;
      #pragma unroll
      for (int n = 0; n < 4; n++) { float pp = expf(s[n][j] - mn); pvv[n][j] = pp; rsum[j] += pp; }
      lo[j] *= al;
      #pragma unroll
      for (int n = 0; n < 4; n++) o[n][j] *= al;
    }
    #pragma unroll
    for (int msk = 1; msk < 16; msk <<= 1)
      #pragma unroll
      for (int j = 0; j < 4; j++) rsum[j] += __shfl_xor(rsum[j], msk, 64);
    #pragma unroll
    for (int j = 0; j < 4; j++) lo[j] += rsum[j];
    int prow = w * 16 + (lane >> 4) * 4;
    #pragma unroll
    for (int n = 0; n < 4; n++)
      #pragma unroll
      for (int j = 0; j < 4; j++) {
        _Float16 hh, ll; split16(pvv[n][j], hh, ll);
        Ph[prow + j][n * 16 + rr] = hh;
        Pl[prow + j][n * 16 + rr] = ll;
      }
    __builtin_amdgcn_s_setprio(1);
    #pragma unroll
    for (int kk = 0; kk < 2; kk++) {
      f16x8 pah = *(const f16x8*)&Ph[w * 16 + rr][kk * 32 + ko];
      f16x8 pal = *(const f16x8*)&Pl[w * 16 + rr][kk * 32 + ko];
      #pragma unroll
      for (int dn = 0; dn < 4; dn++) {
        int ro = (dn * 16 + rr) * 64 + ((kk * 32 + ko) ^ xo8);
        f16x8 vbh = *(const f16x8*)&VhS[ro];
        f16x8 vbl = *(const f16x8*)&VlS[ro];
        o[dn] = mfma16(pah, vbh, o[dn]);
        o[dn] = mfma16(pah, vbl, o[dn]);
        o[dn] = mfma16(pal, vbh, o[dn]);
      }
    }
    __builtin_amdgcn_s_setprio(0);
  }
  float inv[4];
  #pragma unroll
  for (int j = 0; j < 4; j++) inv[j] = 1.0f / lo[j];
  int orow = q0 + w * 16 + (lane >> 4) * 4;
  int ocol = h * 64 + rr;
  #pragma unroll
  for (int dn = 0; dn < 4; dn++)
    #pragma unroll
    for (int j = 0; j < 4; j++) {
      float v = o[dn][j] * inv[j];
      _Float16 hh, ll; split16(v, hh, ll);
      size_t idx = (size_t)((orow + j) * 2 + b) * HH + ocol + dn * 16;
      aoh[idx] = hh; aol[idx] = ll;
    }
}

// ---------------- Router: f32 logits, softmax, top-2, scatter to per-expert lists ----------------
__global__ __launch_bounds__(256) void router_kernel(const float* __restrict__ x,
    const float* __restrict__ rw, int* __restrict__ list, float* __restrict__ listp,
    int* __restrict__ cnt)
{
  __shared__ float rws[HH * 8];
  int tid = threadIdx.x;
  for (int i = tid; i < HH * 8; i += 256) rws[i] = rw[i];
  __syncthreads();
  int t = blockIdx.x * 4 + (tid >> 6);
  int lane = tid & 63;
  const float* xp = x + (size_t)t * HH;
  float acc[8] = {};
  for (int i = lane; i < HH; i += 64) {
    float xv = xp[i];
    #pragma unroll
    for (int e = 0; e < 8; e++) acc[e] += xv * rws[i * 8 + e];
  }
  #pragma unroll
  for (int e = 0; e < 8; e++)
    #pragma unroll
    for (int m = 1; m < 64; m <<= 1) acc[e] += __shfl_xor(acc[e], m, 64);
  if (lane == 0) {
    float mx = acc[0];
    #pragma unroll
    for (int e = 1; e < 8; e++) mx = fmaxf(mx, acc[e]);
    float p[8], sum = 0.f;
    #pragma unroll
    for (int e = 0; e < 8; e++) { p[e] = expf(acc[e] - mx); sum += p[e]; }
    float inv = 1.0f / sum;
    int i1 = 0; float v1 = acc[0];
    #pragma unroll
    for (int e = 1; e < 8; e++) if (acc[e] > v1) { v1 = acc[e]; i1 = e; }
    int i2 = -1; float v2 = -3.4e38f;
    #pragma unroll
    for (int e = 0; e < 8; e++) if (e != i1 && acc[e] > v2) { v2 = acc[e]; i2 = e; }
    int pos1 = atomicAdd(&cnt[i1], 1);
    list[i1 * TT + pos1] = t; listp[i1 * TT + pos1] = p[i1] * inv;
    int pos2 = atomicAdd(&cnt[i2], 1);
    list[i2 * TT + pos2] = t; listp[i2 * TT + pos2] = p[i2] * inv;
  }
}

// ======== MoE GEMMs: 128x128 tile, BK=32, 3-stage LDS pipeline (48KB), depth-2 prefetch ========
// Round-8 configuration restored verbatim (best measured: 661 us total).

// moe1: hidden = gelu(gather(xbf) @ w1T[e]^T). 1D grid, e=id&7 (XCD-pinned).
__global__ __launch_bounds__(256) void moe1_p3(const short* __restrict__ xbf,
    const short* __restrict__ w1T, const int* __restrict__ list,
    const int* __restrict__ cnt, short* __restrict__ hidden)
{
  __shared__ short A3[3][4096], B3[3][4096];   // [128][32] each, 48 KB total
  int id = blockIdx.x;
  int e = id & 7;
  int inner = id >> 3;
  int mx = inner & 31, nx = inner >> 5;
  int ce = cnt[e];
  int m0 = mx * 128;
  if (m0 >= ce) return;                        // block-uniform, before any barrier
  int n0 = nx * 128;
  int off = 0;
  #pragma unroll
  for (int i = 0; i < 8; i++) if (i < e) off += cnt[i];
  const int tid = threadIdx.x, lane = tid & 63, w = tid >> 6;
  const int wr = w >> 1, wc = w & 1;
  f32x4 acc[4][4] = {};
  const short *pa[2], *pb[2];
  int lof[2];
  #pragma unroll
  for (int i = 0; i < 2; i++) {
    int E = i * 2048 + w * 512 + lane * 8;
    int r = E >> 5, c = E & 31;
    int cs = c ^ ((r & 3) << 3);
    int apos = m0 + r; if (apos > ce - 1) apos = ce - 1;
    int tok = list[e * TT + apos];
    pa[i] = xbf + (size_t)tok * HH + cs;
    pb[i] = w1T + ((size_t)e * FF + n0 + r) * HH + cs;
    lof[i] = E;
  }
  const int rr = lane & 15, ko = (lane >> 4) * 8;
  const int koX = ko ^ ((rr & 3) << 3);
  const int T = HH / 32;                       // 32
  // prologue: stage tiles 0,1 into bufs 0,1
  #pragma unroll
  for (int i = 0; i < 2; i++) {
    gload16(pa[i], &A3[0][lof[i]]);
    gload16(pb[i], &B3[0][lof[i]]);
  }
  #pragma unroll
  for (int i = 0; i < 2; i++) {
    gload16(pa[i] + 32, &A3[1][lof[i]]);
    gload16(pb[i] + 32, &B3[1][lof[i]]);
  }
  int cb = 0;
  for (int t = 0; t < T; t++) {
    if (t + 2 < T) {
      int k0 = (t + 2) * 32;
      int nb = cb + 2; if (nb >= 3) nb -= 3;
      #pragma unroll
      for (int i = 0; i < 2; i++) {
        gload16(pa[i] + k0, &A3[nb][lof[i]]);
        gload16(pb[i] + k0, &B3[nb][lof[i]]);
      }
      asm volatile("s_waitcnt vmcnt(8)" ::: "memory");
    } else if (t + 1 < T) {
      asm volatile("s_waitcnt vmcnt(4)" ::: "memory");
    } else {
      asm volatile("s_waitcnt vmcnt(0)" ::: "memory");
    }
    __builtin_amdgcn_s_barrier();
    __builtin_amdgcn_sched_barrier(0);
    bf16x8 fa[4], fb[4];
    #pragma unroll
    for (int m = 0; m < 4; m++) fa[m] = *(const bf16x8*)&A3[cb][(wr * 64 + m * 16 + rr) * 32 + koX];
    #pragma unroll
    for (int n = 0; n < 4; n++) fb[n] = *(const bf16x8*)&B3[cb][(wc * 64 + n * 16 + rr) * 32 + koX];
    __builtin_amdgcn_s_setprio(1);
    #pragma unroll
    for (int m = 0; m < 4; m++)
      #pragma unroll
      for (int n = 0; n < 4; n++) acc[m][n] = mfmabf(fa[m], fb[n], acc[m][n]);
    __builtin_amdgcn_s_setprio(0);
    asm volatile("s_waitcnt lgkmcnt(0)" ::: "memory");
    __builtin_amdgcn_s_barrier();
    __builtin_amdgcn_sched_barrier(0);
    cb += 1; if (cb >= 3) cb -= 3;
  }
  int p0 = m0 + wr * 64 + (lane >> 4) * 4;
  int c0 = n0 + wc * 64 + (lane & 15);
  #pragma unroll
  for (int m = 0; m < 4; m++)
    #pragma unroll
    for (int n = 0; n < 4; n++)
      #pragma unroll
      for (int j = 0; j < 4; j++) {
        int pos = p0 + m * 16 + j;
        if (pos < ce) {
          float v = fast_gelu(acc[m][n][j]);
          hidden[(size_t)(off + pos) * FF + c0 + n * 16] = f2bf(v);
        }
      }
}

// moe2: out[tok] += p * (hidden @ w2T[e]^T), split-K x2, atomic epilogue.
// id: e=id&7; r=id>>3: mx=r&31, nx=(r>>5)&7, ksp=r>>8.
__global__ __launch_bounds__(256) void moe2_p3(const short* __restrict__ hidden,
    const short* __restrict__ w2T, const int* __restrict__ list,
    const float* __restrict__ listp, const int* __restrict__ cnt,
    float* __restrict__ outp)
{
  __shared__ short A3[3][4096], B3[3][4096];
  int id = blockIdx.x;
  int e = id & 7;
  int r_ = id >> 3;
  int mx = r_ & 31, nx = (r_ >> 5) & 7, ksp = r_ >> 8;
  int ce = cnt[e];
  int m0 = mx * 128;
  if (m0 >= ce) return;
  int n0 = nx * 128;
  int kbase = ksp * (FF / 2);
  int off = 0;
  #pragma unroll
  for (int i = 0; i < 8; i++) if (i < e) off += cnt[i];
  const int tid = threadIdx.x, lane = tid & 63, w = tid >> 6;
  const int wr = w >> 1, wc = w & 1;
  f32x4 acc[4][4] = {};
  const short *pa[2], *pb[2];
  int lof[2];
  #pragma unroll
  for (int i = 0; i < 2; i++) {
    int E = i * 2048 + w * 512 + lane * 8;
    int r = E >> 5, c = E & 31;
    int cs = c ^ ((r & 3) << 3);
    int apos = m0 + r; if (apos > ce - 1) apos = ce - 1;
    pa[i] = hidden + ((size_t)off + apos) * FF + kbase + cs;
    pb[i] = w2T + ((size_t)e * HH + n0 + r) * FF + kbase + cs;
    lof[i] = E;
  }
  const int rr = lane & 15, ko = (lane >> 4) * 8;
  const int koX = ko ^ ((rr & 3) << 3);
  const int T = (FF / 2) / 32;                 // 64
  #pragma unroll
  for (int i = 0; i < 2; i++) {
    gload16(pa[i], &A3[0][lof[i]]);
    gload16(pb[i], &B3[0][lof[i]]);
  }
  #pragma unroll
  for (int i = 0; i < 2; i++) {
    gload16(pa[i] + 32, &A3[1][lof[i]]);
    gload16(pb[i] + 32, &B3[1][lof[i]]);
  }
  int cb = 0;
  for (int t = 0; t < T; t++) {
    if (t + 2 < T) {
      int k0 = (t + 2) * 32;
      int nb = cb + 2; if (nb >= 3) nb -= 3;
      #pragma unroll
      for (int i = 0; i < 2; i++) {
        gload16(pa[i] + k0, &A3[nb][lof[i]]);
        gload16(pb[i] + k0, &B3[nb][lof[i]]);
      }
      asm volatile("s_waitcnt vmcnt(8)" ::: "memory");
    } else if (t + 1 < T) {
      asm volatile("s_waitcnt vmcnt(4)" ::: "memory");
    } else {
      asm volatile("s_waitcnt vmcnt(0)" ::: "memory");
    }
    __builtin_amdgcn_s_barrier();
    __builtin_amdgcn_sched_barrier(0);
    bf16x8 fa[4], fb[4];
    #pragma unroll
    for (int m = 0; m < 4; m++) fa[m] = *(const bf16x8*)&A3[cb][(wr * 64 + m * 16 + rr) * 32 + koX];
    #pragma unroll
    for (int n = 0; n < 4; n++) fb[n] = *(const bf16x8*)&B3[cb][(wc * 64 + n * 16 + rr) * 32 + koX];
    __builtin_amdgcn_s_setprio(1);
    #pragma unroll
    for (int m = 0; m < 4; m++)
      #pragma unroll
      for (int n = 0; n < 4; n++) acc[m][n] = mfmabf(fa[m], fb[n], acc[m][n]);
    __builtin_amdgcn_s_setprio(0);
    asm volatile("s_waitcnt lgkmcnt(0)" ::: "memory");
    __builtin_amdgcn_s_barrier();
    __builtin_amdgcn_sched_barrier(0);
    cb += 1; if (cb >= 3) cb -= 3;
  }
  int p0 = m0 + wr * 64 + (lane >> 4) * 4;
  int c0 = n0 + wc * 64 + (lane & 15);
  #pragma unroll
  for (int m = 0; m < 4; m++)
    #pragma unroll
    for (int j = 0; j < 4; j++) {
      int pos = p0 + m * 16 + j;
      if (pos < ce) {
        int tk = list[e * TT + pos];
        float pw = listp[e * TT + pos];
        #pragma unroll
        for (int n = 0; n < 4; n++)
          atomicAdd(&outp[(size_t)tk * HH + c0 + n * 16], pw * acc[m][n][j]);
      }
    }
}

// ---------------- fallback MoE kernels (round-1, known-good; used when ws is small) -----------
__global__ __launch_bounds__(256) void moe_gemm1(const float* __restrict__ x,
    const float* __restrict__ w1, const int* __restrict__ list,
    const int* __restrict__ cnt, short* __restrict__ hidden, int e)
{
  int ce = cnt[e];
  int m0 = blockIdx.y * 128;
  if (m0 >= ce) return;
  int n0 = blockIdx.x * 128;
  __shared__ short As[128][40], Bs[128][40];
  int tid = threadIdx.x, lane = tid & 63, w = tid >> 6, wr = w >> 1, wc = w & 1;
  f32x4 acc[4][4] = {};
  int arow = tid >> 1, akh = (tid & 1) * 16;
  int apos = m0 + arow;
  int tok = list[(size_t)e * TT + (apos < ce ? apos : 0)];
  const float* ap = x + (size_t)tok * HH + akh;
  int bn = tid & 127, bkh = (tid >> 7) * 16;
  const float* bp = w1 + (size_t)e * HH * FF + (size_t)bkh * FF + n0 + bn;
  for (int k0 = 0; k0 < HH; k0 += 32) {
    __syncthreads();
    {
      const float4* p = (const float4*)(ap + k0);
      bf16x8 s0, s1;
      #pragma unroll
      for (int q = 0; q < 2; q++) { float4 v = p[q]; s0[q*4] = f2bf(v.x); s0[q*4+1] = f2bf(v.y); s0[q*4+2] = f2bf(v.z); s0[q*4+3] = f2bf(v.w); }
      #pragma unroll
      for (int q = 0; q < 2; q++) { float4 v = p[q+2]; s1[q*4] = f2bf(v.x); s1[q*4+1] = f2bf(v.y); s1[q*4+2] = f2bf(v.z); s1[q*4+3] = f2bf(v.w); }
      *(bf16x8*)&As[arow][akh] = s0; *(bf16x8*)&As[arow][akh+8] = s1;
    }
    {
      const float* p = bp + (size_t)k0 * FF;
      bf16x8 s0, s1;
      #pragma unroll
      for (int q = 0; q < 8; q++) s0[q] = f2bf(p[(size_t)q * FF]);
      #pragma unroll
      for (int q = 0; q < 8; q++) s1[q] = f2bf(p[(size_t)(q+8) * FF]);
      *(bf16x8*)&Bs[bn][bkh] = s0; *(bf16x8*)&Bs[bn][bkh+8] = s1;
    }
    __syncthreads();
    int rr = lane & 15, ko = (lane >> 4) * 8;
    bf16x8 fa[4], fb[4];
    #pragma unroll
    for (int m = 0; m < 4; m++) fa[m] = *(bf16x8*)&As[wr*64 + m*16 + rr][ko];
    #pragma unroll
    for (int n = 0; n < 4; n++) fb[n] = *(bf16x8*)&Bs[wc*64 + n*16 + rr][ko];
    #pragma unroll
    for (int m = 0; m < 4; m++)
      #pragma unroll
      for (int n = 0; n < 4; n++) acc[m][n] = mfmabf(fa[m], fb[n], acc[m][n]);
  }
  int p0 = m0 + wr*64 + (lane >> 4) * 4;
  int c0 = n0 + wc*64 + (lane & 15);
  #pragma unroll
  for (int m = 0; m < 4; m++)
    #pragma unroll
    for (int n = 0; n < 4; n++)
      #pragma unroll
      for (int j = 0; j < 4; j++) {
        int pos = p0 + m*16 + j;
        if (pos < ce) {
          float v = acc[m][n][j];
          v = 0.5f * v * (1.0f + erff(v * 0.70710678f));
          hidden[(size_t)pos * FF + c0 + n*16] = f2bf(v);
        }
      }
}

__global__ __launch_bounds__(256) void moe_gemm2(const short* __restrict__ hidden,
    const float* __restrict__ w2, const int* __restrict__ list,
    const float* __restrict__ listp, const int* __restrict__ cnt,
    float* __restrict__ outp, int e)
{
  int ce = cnt[e];
  int m0 = blockIdx.y * 128;
  if (m0 >= ce) return;
  int n0 = blockIdx.x * 128;
  __shared__ short As[128][40], Bs[128][40];
  int tid = threadIdx.x, lane = tid & 63, w = tid >> 6, wr = w >> 1, wc = w & 1;
  f32x4 acc[4][4] = {};
  int arow = tid >> 1, akh = (tid & 1) * 16;
  int apos = m0 + arow;
  const short* ap = hidden + (size_t)(apos < ce ? apos : 0) * FF + akh;
  int bn = tid & 127, bkh = (tid >> 7) * 16;
  const float* bp = w2 + (size_t)e * FF * HH + (size_t)bkh * HH + n0 + bn;
  for (int k0 = 0; k0 < FF; k0 += 32) {
    __syncthreads();
    {
      const int4* p = (const int4*)(ap + k0);
      int4 a0 = p[0], a1 = p[1];
      *(int4*)&As[arow][akh]   = a0;
      *(int4*)&As[arow][akh+8] = a1;
    }
    {
      const float* p = bp + (size_t)k0 * HH;
      bf16x8 s0, s1;
      #pragma unroll
      for (int q = 0; q < 8; q++) s0[q] = f2bf(p[(size_t)q * HH]);
      #pragma unroll
      for (int q = 0; q < 8; q++) s1[q] = f2bf(p[(size_t)(q+8) * HH]);
      *(bf16x8*)&Bs[bn][bkh] = s0; *(bf16x8*)&Bs[bn][bkh+8] = s1;
    }
    __syncthreads();
    int rr = lane & 15, ko = (lane >> 4) * 8;
    bf16x8 fa[4], fb[4];
    #pragma unroll
    for (int m = 0; m < 4; m++) fa[m] = *(bf16x8*)&As[wr*64 + m*16 + rr][ko];
    #pragma unroll
    for (int n = 0; n < 4; n++) fb[n] = *(bf16x8*)&Bs[wc*64 + n*16 + rr][ko];
    #pragma unroll
    for (int m = 0; m < 4; m++)
      #pragma unroll
      for (int n = 0; n < 4; n++) acc[m][n] = mfmabf(fa[m], fb[n], acc[m][n]);
  }
  int p0 = m0 + wr*64 + (lane >> 4) * 4;
  int c0 = n0 + wc*64 + (lane & 15);
  #pragma unroll
  for (int m = 0; m < 4; m++)
    #pragma unroll
    for (int j = 0; j < 4; j++) {
      int pos = p0 + m*16 + j;
      if (pos < ce) {
        int tk = list[(size_t)e * TT + pos];
        float pw = listp[(size_t)e * TT + pos];
        #pragma unroll
        for (int n = 0; n < 4; n++)
          atomicAdd(&outp[(size_t)tk * HH + c0 + n*16], pw * acc[m][n][j]);
      }
    }
}

extern "C" void kernel_launch(void* const* d_in, const int* in_sizes, int n_in,
                              void* d_out, int out_size, void* d_ws, size_t ws_size,
                              hipStream_t stream)
{
  const float* hs      = (const float*)d_in[0];
  const float* ln1w    = (const float*)d_in[1];
  const float* ln1b    = (const float*)d_in[2];
  const float* ln2w    = (const float*)d_in[3];
  const float* ln2b    = (const float*)d_in[4];
  const float* qkvw    = (const float*)d_in[5];
  const float* projw   = (const float*)d_in[6];
  const float* routerw = (const float*)d_in[7];
  const float* w1      = (const float*)d_in[8];
  const float* w2      = (const float*)d_in[9];
  float* out = (float*)d_out;

  const size_t MB = 1024 * 1024;
  char* wsb = (char*)d_ws;
  bool full = ws_size >= 153 * MB;

  float*    qkvbuf = (float*)wsb;
  _Float16* khb    = (_Float16*)(wsb + 24 * MB);
  _Float16* klb    = (_Float16*)(wsb + 26 * MB);
  _Float16* vhb    = (_Float16*)(wsb + 28 * MB);
  _Float16* vlb    = (_Float16*)(wsb + 30 * MB);
  short*    hidden = (short*)wsb;
  size_t r2 = full ? 64 * MB : 32 * MB;
  _Float16* ln1h = (_Float16*)(wsb + r2);
  _Float16* ln1l = (_Float16*)(wsb + r2 + 8 * MB);
  _Float16* aohb = ln1h;
  _Float16* aolb = ln1l;
  float*    xbuf = (float*)(wsb + r2);
  short*    xbf  = (short*)(wsb + r2 + 16 * MB);
  size_t r3 = full ? 88 * MB : 56 * MB;
  _Float16* qkvwTh  = (_Float16*)(wsb + r3);
  _Float16* qkvwTl  = (_Float16*)(wsb + r3 + 3 * MB);
  _Float16* projwTh = (_Float16*)(wsb + r3 + 6 * MB);
  _Float16* projwTl = (_Float16*)(wsb + r3 + 8 * MB);
  short*    w1T     = (short*)(wsb + r3);
  short*    w2T     = (short*)(wsb + r3);
  size_t r4 = full ? 152 * MB : 66 * MB;
  int*   list  = (int*)(wsb + r4);
  float* listp = (float*)(wsb + r4 + 128 * 1024);
  int*   cnt   = (int*)(wsb + r4 + 256 * 1024);

  zero_cnt<<<1, 64, 0, stream>>>(cnt);
  wconv_split<<<dim3(QKVN / 64, HH / 64), 256, 0, stream>>>(qkvw, qkvwTh, qkvwTl, HH, QKVN);
  wconv_split<<<dim3(HH / 64, HH / 64), 256, 0, stream>>>(projw, projwTh, projwTl, HH, HH);
  ln_split<0><<<TT, 256, 0, stream>>>(hs, ln1w, ln1b, ln1h, ln1l, nullptr, nullptr);
  gemm_split2<0><<<dim3(QKVN / 128, TT / 128), 256, 0, stream>>>(
      ln1h, ln1l, qkvwTh, qkvwTl, HH, qkvbuf, QKVN, nullptr, khb, klb);
  vtrans<<<dim3(8, 32), 256, 0, stream>>>(qkvbuf, vhb, vlb);
  attn2<<<dim3(32, 32), 256, 0, stream>>>(qkvbuf, khb, klb, vhb, vlb, aohb, aolb);
  gemm_split2<1><<<dim3(HH / 128, TT / 128), 256, 0, stream>>>(
      aohb, aolb, projwTh, projwTl, HH, out, HH, hs, nullptr, nullptr);
  ln_split<1><<<TT, 256, 0, stream>>>(out, ln2w, ln2b, nullptr, nullptr, xbuf, xbf);
  router_kernel<<<TT / 4, 256, 0, stream>>>(xbuf, routerw, list, listp, cnt);
  if (full) {
    wconv_bf<<<dim3(FF / 64, HH / 64, 8), 256, 0, stream>>>(w1, w1T, HH, FF);
    moe1_p3<<<8 * 32 * 32, 256, 0, stream>>>(xbf, w1T, list, cnt, hidden);
    wconv_bf<<<dim3(HH / 64, FF / 64, 8), 256, 0, stream>>>(w2, w2T, FF, HH);
    moe2_p3<<<8 * 32 * 8 * 2, 256, 0, stream>>>(hidden, w2T, list, listp, cnt, out);
  } else {
    for (int e = 0; e < 8; e++) {
      moe_gemm1<<<dim3(FF / 128, TT / 128), 256, 0, stream>>>(xbuf, w1, list, cnt, hidden, e);
      moe_gemm2<<<dim3(HH / 128, TT / 128), 256, 0, stream>>>(hidden, w2, list, listp, cnt, out, e);
    }
  }
}